// Round 6
// baseline (190.055 us; speedup 1.0000x reference)
//
#include <hip/hip_runtime.h>
#include <hip/hip_fp16.h>

// GLOBE_61864708931733 — R22: NO launch attribute on globe_mfma (default).
// R21 post-mortem (120us, spill again): amdgpu_waves_per_eu(4) ALSO forced
// VGPR 116->64 (cap ~ 256/min_waves on this compiler for MFMA kernels) ->
// same 450MB scratch traffic. Mapped: min-waves>=4 requests are unusable at
// 116 natural VGPRs. BUT both R20/R21 show the waves-per-eu metadata DOES
// move runtime residency (Occ 15.8 -> 37/42%). The ONE config never tested
// in either session: no attribute at all. Default: flat-wg 1024 -> VGPR cap
// 128 >= 116 (codegen unchanged, no spill), and NO waves-per-eu residency
// clamp. R22 = R19 byte-identical except the attr deleted.
// Predicted if cap real: VGPR 116, FETCH ~500KB, Occ 35-50%, globe 42-48us.
// If neutral (~57us, Occ ~16%): attr-cap story dead -> next: skewed-chunk
// in-wave pipeline.

#define N_T 2048
#define N_S 512
#define BLK 128
#define SCALE 2.885390081777927f   // 2*log2(e)

// d_ws: 4 copies, stride 5888 floats (23552 B):
//   units 0..21: f16x4-frag pairs, unit u = [64 lanes][16 B]
//     u 0..1:  W1 (unit0: mt0 lo / mt1 hi; unit1: mt2/mt3), kt=0 only
//     u 2..9:  W2' = -2*W2*SCALE: unit 2+mt*2+kp = K=32 frag (mt, kk=kp) f16x8
//     u 10..17: W3' same
//     u 18..19: Wout' hi | u 20..21: Wout' lo   (Wout' = -2*Wout, unscaled)
//   floats 5632..5823: scaled biases [3][64]; b2',b3' include +colsum(W)
//   floats 5824..5826: bout' = bout + colsum(Wout)  (unscaled)
#define CPY_F 5888     // floats per copy
#define CPY_U 1472     // 16B units per copy

typedef _Float16 f16;
typedef _Float16 f16x4 __attribute__((ext_vector_type(4)));
typedef _Float16 f16x8 __attribute__((ext_vector_type(8)));
typedef float f32x4 __attribute__((ext_vector_type(4)));
typedef unsigned short u16;
typedef unsigned int u32;

__device__ __forceinline__ float zsig(float x) {
    // x is SCALE*y; z = 1/(2^x+1); consumer weights are folded so t = 1-2z.
    float e = __builtin_amdgcn_exp2f(x);
    return __builtin_amdgcn_rcpf(e + 1.0f);
}

__device__ __forceinline__ f32x4 mfma16(f16x4 a, f16x4 b, f32x4 c) {
    return __builtin_amdgcn_mfma_f32_16x16x16f16(a, b, c, 0, 0, 0);
}
__device__ __forceinline__ f32x4 mfma32(f16x8 a, f16x8 b, f32x4 c) {
    return __builtin_amdgcn_mfma_f32_16x16x32_f16(a, b, c, 0, 0, 0);
}

__device__ __forceinline__ u32 pkrtz(float a, float b) {
    return __builtin_bit_cast(u32, __builtin_amdgcn_cvt_pkrtz(a, b));
}

__device__ __forceinline__ f16x4 lo4(uint4 g) {
    uint2 p; p.x = g.x; p.y = g.y;
    return __builtin_bit_cast(f16x4, p);
}
__device__ __forceinline__ f16x4 hi4(uint4 g) {
    uint2 p; p.x = g.z; p.y = g.w;
    return __builtin_bit_cast(f16x4, p);
}
__device__ __forceinline__ f16x8 all8(uint4 g) {
    return __builtin_bit_cast(f16x8, g);
}

// 8 z-sigmoids -> one K=32 B-frag (f16x8) built directly as a uint4.
__device__ __forceinline__ f16x8 tpack8(f32x4 cl, f32x4 ch) {
    uint4 p;
    p.x = pkrtz(zsig(cl[0]), zsig(cl[1]));
    p.y = pkrtz(zsig(cl[2]), zsig(cl[3]));
    p.z = pkrtz(zsig(ch[0]), zsig(ch[1]));
    p.w = pkrtz(zsig(ch[2]), zsig(ch[3]));
    return __builtin_bit_cast(f16x8, p);
}

__global__ __launch_bounds__(256) void prep_kernel(
    const float* __restrict__ W1, const float* __restrict__ b1,
    const float* __restrict__ W2, const float* __restrict__ b2,
    const float* __restrict__ W3, const float* __restrict__ b3,
    const float* __restrict__ Wout, const float* __restrict__ bout,
    float* __restrict__ ws)
{
    const int tid = blockIdx.x * 256 + threadIdx.x;   // grid 26*256 = 6656
    if (tid < 5632) {                                 // 4 copies * 22 units * 64
        const int cpy = tid / 1408;
        const int r   = tid - cpy * 1408;
        const int u   = r >> 6, lane = r & 63;
        const int q = lane >> 4, l15 = lane & 15;
        float x[8];
        bool lo = false;
        #pragma unroll
        for (int e = 0; e < 8; ++e) {
            const int half = e >> 2, j = e & 3;
            float v;
            if (u < 2) {                       // W1: kt=0; frags mt = u*2+half
                const int mt = u * 2 + half;
                const int k = q * 4 + j;
                v = (k < 7) ? W1[k * 64 + mt * 16 + l15] * SCALE : 0.f;
            } else if (u < 10) {               // W2' = -2*W2*SCALE
                const int idx = u - 2, mt = idx >> 1, kp = idx & 1;
                const int k = (kp * 2 + half) * 16 + q * 4 + j;
                v = -2.0f * W2[k * 64 + mt * 16 + l15] * SCALE;
            } else if (u < 18) {               // W3' = -2*W3*SCALE
                const int idx = u - 10, mt = idx >> 1, kp = idx & 1;
                const int k = (kp * 2 + half) * 16 + q * 4 + j;
                v = -2.0f * W3[k * 64 + mt * 16 + l15] * SCALE;
            } else {                           // Wout' hi (18,19) / lo (20,21)
                const int kp = (u - 18) & 1;
                const int k = (kp * 2 + half) * 16 + q * 4 + j;
                v = (l15 < 3) ? -2.0f * Wout[k * 3 + l15] : 0.f;
                lo = (u >= 20);
            }
            x[e] = v;
        }
        u16 outw[8];
        #pragma unroll
        for (int e = 0; e < 8; ++e) {
            const f16 h = (f16)x[e];
            const f16 val = lo ? (f16)(x[e] - (float)h) : h;
            outw[e] = __builtin_bit_cast(u16, val);
        }
        uint4 g;
        g.x = outw[0] | ((u32)outw[1] << 16);
        g.y = outw[2] | ((u32)outw[3] << 16);
        g.z = outw[4] | ((u32)outw[5] << 16);
        g.w = outw[6] | ((u32)outw[7] << 16);
        *(uint4*)((char*)ws + (size_t)cpy * CPY_F * 4 + (size_t)(u * 64 + lane) * 16) = g;
    } else if (tid < 6412) {                   // biases: 4 copies * 195
        const int b = tid - 5632;
        const int cpy = b / 195, i = b - cpy * 195;
        if (i < 192) {
            const int Lb = i >> 6, j = i & 63;
            float bv;
            if (Lb == 0) {
                bv = b1[j];
            } else if (Lb == 1) {              // b2' = b2 + colsum(W2)
                bv = b2[j];
                for (int k = 0; k < 64; ++k) bv += W2[k * 64 + j];
            } else {                           // b3' = b3 + colsum(W3)
                bv = b3[j];
                for (int k = 0; k < 64; ++k) bv += W3[k * 64 + j];
            }
            ws[cpy * CPY_F + 5632 + i] = bv * SCALE;
        } else {                               // bout' = bout + colsum(Wout)
            const int c3 = i - 192;            // 0..2
            float bv = bout[c3];
            for (int k = 0; k < 64; ++k) bv += Wout[k * 3 + c3];
            ws[cpy * CPY_F + 5824 + c3] = bv;  // unscaled
        }
    }
}

__global__ void globe_mfma(
    const float* __restrict__ pts, const float* __restrict__ ctr,
    const float* __restrict__ nrm, const float* __restrict__ areas,
    const float* __restrict__ rlen, const float* __restrict__ bout,
    const float* __restrict__ p_scale, const float* __restrict__ p_bias,
    const float* __restrict__ v_scale, const float* __restrict__ v_bias,
    const float* __restrict__ ws,
    float* __restrict__ out)
{
    __shared__ __align__(16) u16 featL[2][2][64][8];   // [wave][stream]
    __shared__ __align__(16) uint4 geomL[2][2][64];
    __shared__ float xr[4];

    const int tid  = threadIdx.x;
    const int lane = tid & 63;
    const int wv   = tid >> 6;
    const int l15  = lane & 15;
    const int q    = lane >> 4;
    const int qf   = q & 1;                          // clamped feature octet
    const int t    = blockIdx.x;                     // both waves: same target

    const float px = pts[3 * t + 0], py = pts[3 * t + 1], pz = pts[3 * t + 2];
    const float invL0 = __builtin_amdgcn_rcpf(rlen[0]);
    const float invL1 = __builtin_amdgcn_rcpf(rlen[1]);
    f32x4 co_init = (f32x4){0.f, 0.f, 0.f, 0.f};
    if (q == 0) { co_init[0] = ws[5824]; co_init[1] = ws[5825]; co_init[2] = ws[5826]; }

    const f16x4 bz = (f16x4){0, 0, 0, 0};
    float accp = 0.f, avx = 0.f, avy = 0.f, avz = 0.f;

    const int stag = (wv + (int)blockIdx.x) & 1;     // phase stagger

    #pragma unroll 1
    for (int cc = 0; cc < 2; ++cc) {
        const int ch = cc ^ stag;
        // chunk-dependent weight copy (copies 0,2 used): defeats LICM
        const uint4* __restrict__ wsU = (const uint4*)ws + (ch * 2) * CPY_U;
        const float* __restrict__ wsBias = ws + (ch * 2) * CPY_F + 5632;

        // ---- features + geometry for BOTH streams ----
        #pragma unroll
        for (int st = 0; st < 2; ++st) {
            const int s = (wv * 4 + ch * 2 + st) * 64 + lane;
            const float cx = ctr[3 * s + 0], cy = ctr[3 * s + 1], cz = ctr[3 * s + 2];
            const float snx = nrm[3 * s + 0], sny = nrm[3 * s + 1], snz = nrm[3 * s + 2];
            const float ar = areas[s];
            const float rvx = px - cx, rvy = py - cy, rvz = pz - cz;
            const float r2 = rvx * rvx + rvy * rvy + rvz * rvz;
            const float r2e = r2 + 1e-8f;
            const float rinv = __builtin_amdgcn_rsqf(r2e);
            const float r = r2e * rinv;
            const float rhx = rvx * rinv, rhy = rvy * rinv, rhz = rvz * rinv;
            const float cth = rhx * snx + rhy * sny + rhz * snz;
            const float c2 = cth * cth;
            const float decay = ar * __builtin_amdgcn_rcpf(r2 + 1.0f);
            uint4 fw;
            fw.x = pkrtz(__builtin_amdgcn_rcpf(fmaf(r, invL0, 1.0f)),
                         __builtin_amdgcn_rcpf(fmaf(r, invL1, 1.0f)));
            fw.y = pkrtz(1.0f, cth);
            fw.z = pkrtz(fmaf(1.5f, c2, -0.5f), cth * fmaf(2.5f, c2, -1.5f));
            fw.w = pkrtz(__logf(ar), 0.0f);
            *(uint4*)&featL[wv][st][lane][0] = fw;
            uint4 g;
            g.x = __builtin_bit_cast(u32, decay);
            g.y = pkrtz(rhx, rhy);
            g.z = pkrtz(rhz, snx);
            g.w = pkrtz(sny, snz);
            geomL[wv][st][lane] = g;
        }

        // ---- layer 1 (16x16x16, K=7 padded; shared frags, both streams) ----
        f16x8 B2[2][2][4];   // [stream][kk][n4]  (K=32 z-frags for layer 2)
        {
            const uint4 g0 = wsU[0 * 64 + lane], g1 = wsU[1 * 64 + lane];
            f16x4 a1[4];
            a1[0] = lo4(g0); a1[1] = hi4(g0); a1[2] = lo4(g1); a1[3] = hi4(g1);
            float4 bv[4];
            #pragma unroll
            for (int mt = 0; mt < 4; ++mt)
                bv[mt] = *(const float4*)(wsBias + 0 * 64 + mt * 16 + q * 4);
            #pragma unroll
            for (int n4 = 0; n4 < 4; ++n4) {
                f16x4 bf[2];
                #pragma unroll
                for (int st = 0; st < 2; ++st) {
                    const f16x4 lv = *(const f16x4*)&featL[wv][st][n4 * 16 + l15][qf * 4];
                    bf[st] = (q < 2) ? lv : bz;
                }
                f32x4 c[2][4];
                #pragma unroll
                for (int mt = 0; mt < 4; ++mt) {
                    c[0][mt] = (f32x4){bv[mt].x, bv[mt].y, bv[mt].z, bv[mt].w};
                    c[1][mt] = c[0][mt];
                    c[0][mt] = mfma16(a1[mt], bf[0], c[0][mt]);
                    c[1][mt] = mfma16(a1[mt], bf[1], c[1][mt]);
                }
                #pragma unroll
                for (int kk = 0; kk < 2; ++kk) {
                    B2[0][kk][n4] = tpack8(c[0][2 * kk], c[0][2 * kk + 1]);
                    B2[1][kk][n4] = tpack8(c[1][2 * kk], c[1][2 * kk + 1]);
                }
            }
        }

        // ---- layer 2 (16x16x32) ----
        f16x8 B3[2][2][4];
        {
            f16x8 a[4][2];
            #pragma unroll
            for (int mt = 0; mt < 4; ++mt) {
                a[mt][0] = all8(wsU[(2 + 2 * mt) * 64 + lane]);
                a[mt][1] = all8(wsU[(3 + 2 * mt) * 64 + lane]);
            }
            float4 bv[4];
            #pragma unroll
            for (int mt = 0; mt < 4; ++mt)
                bv[mt] = *(const float4*)(wsBias + 1 * 64 + mt * 16 + q * 4);
            #pragma unroll
            for (int n4 = 0; n4 < 4; ++n4) {
                f32x4 c[2][4];
                #pragma unroll
                for (int mt = 0; mt < 4; ++mt) {
                    c[0][mt] = (f32x4){bv[mt].x, bv[mt].y, bv[mt].z, bv[mt].w};
                    c[1][mt] = c[0][mt];
                }
                #pragma unroll
                for (int kk = 0; kk < 2; ++kk)
                    #pragma unroll
                    for (int mt = 0; mt < 4; ++mt) {
                        c[0][mt] = mfma32(a[mt][kk], B2[0][kk][n4], c[0][mt]);
                        c[1][mt] = mfma32(a[mt][kk], B2[1][kk][n4], c[1][mt]);
                    }
                #pragma unroll
                for (int kk = 0; kk < 2; ++kk) {
                    B3[0][kk][n4] = tpack8(c[0][2 * kk], c[0][2 * kk + 1]);
                    B3[1][kk][n4] = tpack8(c[1][2 * kk], c[1][2 * kk + 1]);
                }
            }
        }

        // ---- layer 3 (16x16x32) ----
        f16x8 BO[2][2][4];
        {
            f16x8 a[4][2];
            #pragma unroll
            for (int mt = 0; mt < 4; ++mt) {
                a[mt][0] = all8(wsU[(10 + 2 * mt) * 64 + lane]);
                a[mt][1] = all8(wsU[(11 + 2 * mt) * 64 + lane]);
            }
            float4 bv[4];
            #pragma unroll
            for (int mt = 0; mt < 4; ++mt)
                bv[mt] = *(const float4*)(wsBias + 2 * 64 + mt * 16 + q * 4);
            #pragma unroll
            for (int n4 = 0; n4 < 4; ++n4) {
                f32x4 c[2][4];
                #pragma unroll
                for (int mt = 0; mt < 4; ++mt) {
                    c[0][mt] = (f32x4){bv[mt].x, bv[mt].y, bv[mt].z, bv[mt].w};
                    c[1][mt] = c[0][mt];
                }
                #pragma unroll
                for (int kk = 0; kk < 2; ++kk)
                    #pragma unroll
                    for (int mt = 0; mt < 4; ++mt) {
                        c[0][mt] = mfma32(a[mt][kk], B3[0][kk][n4], c[0][mt]);
                        c[1][mt] = mfma32(a[mt][kk], B3[1][kk][n4], c[1][mt]);
                    }
                #pragma unroll
                for (int kk = 0; kk < 2; ++kk) {
                    BO[0][kk][n4] = tpack8(c[0][2 * kk], c[0][2 * kk + 1]);
                    BO[1][kk][n4] = tpack8(c[1][2 * kk], c[1][2 * kk + 1]);
                }
            }
        }

        // ---- output layer (16x16x32, hi+lo) + decay-weighted accumulation ----
        {
            const f16x8 aoh0 = all8(wsU[18 * 64 + lane]);
            const f16x8 aoh1 = all8(wsU[19 * 64 + lane]);
            const f16x8 aol0 = all8(wsU[20 * 64 + lane]);
            const f16x8 aol1 = all8(wsU[21 * 64 + lane]);
            #pragma unroll
            for (int n4 = 0; n4 < 4; ++n4) {
                f32x4 co[2];
                co[0] = co_init; co[1] = co_init;
                co[0] = mfma32(aoh0, BO[0][0][n4], co[0]);
                co[1] = mfma32(aoh0, BO[1][0][n4], co[1]);
                co[0] = mfma32(aol0, BO[0][0][n4], co[0]);
                co[1] = mfma32(aol0, BO[1][0][n4], co[1]);
                co[0] = mfma32(aoh1, BO[0][1][n4], co[0]);
                co[1] = mfma32(aoh1, BO[1][1][n4], co[1]);
                co[0] = mfma32(aol1, BO[0][1][n4], co[0]);
                co[1] = mfma32(aol1, BO[1][1][n4], co[1]);
                if (q == 0) {
                    #pragma unroll
                    for (int st = 0; st < 2; ++st) {
                        const uint4 g = geomL[wv][st][n4 * 16 + l15];
                        const float d = __builtin_bit_cast(float, g.x);
                        const float2 rxy = __half22float2(__builtin_bit_cast(__half2, g.y));
                        const float2 rzx = __half22float2(__builtin_bit_cast(__half2, g.z));
                        const float2 nyz = __half22float2(__builtin_bit_cast(__half2, g.w));
                        const float o0 = co[st][0], o1 = co[st][1], o2 = co[st][2];
                        accp = fmaf(o0, d, accp);
                        avx  = fmaf(fmaf(o1, rxy.x, o2 * rzx.y), d, avx);
                        avy  = fmaf(fmaf(o1, rxy.y, o2 * nyz.x), d, avy);
                        avz  = fmaf(fmaf(o1, rzx.x, o2 * nyz.y), d, avz);
                    }
                }
            }
        }
    }

    // ---- reduce across the 16 accumulating lanes ----
    #pragma unroll
    for (int off = 8; off > 0; off >>= 1) {
        accp += __shfl_down(accp, off);
        avx  += __shfl_down(avx,  off);
        avy  += __shfl_down(avy,  off);
        avz  += __shfl_down(avz,  off);
    }

    // ---- cross-wave combine ----
    if (wv == 1 && lane == 0) {
        xr[0] = accp; xr[1] = avx; xr[2] = avy; xr[3] = avz;
    }
    __syncthreads();
    if (wv == 0 && lane == 0) {
        accp += xr[0]; avx += xr[1]; avy += xr[2]; avz += xr[3];
        const float ps = p_scale[0], pb = p_bias[0];
        const float vs = v_scale[0], vb = v_bias[0];
        out[4 * t + 0] = fmaf(accp, ps, pb);
        out[4 * t + 1] = fmaf(avx, vs, vb);
        out[4 * t + 2] = fmaf(avy, vs, vb);
        out[4 * t + 3] = fmaf(avz, vs, vb);
    }
}

extern "C" void kernel_launch(void* const* d_in, const int* in_sizes, int n_in,
                              void* d_out, int out_size, void* d_ws, size_t ws_size,
                              hipStream_t stream) {
    (void)in_sizes; (void)n_in; (void)ws_size; (void)out_size;
    const float* pts   = (const float*)d_in[0];
    const float* ctr   = (const float*)d_in[1];
    const float* nrm   = (const float*)d_in[2];
    const float* areas = (const float*)d_in[3];
    const float* rlen  = (const float*)d_in[4];
    const float* W1    = (const float*)d_in[5];
    const float* b1    = (const float*)d_in[6];
    const float* W2    = (const float*)d_in[7];
    const float* b2    = (const float*)d_in[8];
    const float* W3    = (const float*)d_in[9];
    const float* b3    = (const float*)d_in[10];
    const float* Wout  = (const float*)d_in[11];
    const float* bout  = (const float*)d_in[12];
    const float* ps    = (const float*)d_in[13];
    const float* pb    = (const float*)d_in[14];
    const float* vs    = (const float*)d_in[15];
    const float* vb    = (const float*)d_in[16];
    float* ws = (float*)d_ws;

    prep_kernel<<<26, 256, 0, stream>>>(W1, b1, W2, b2, W3, b3, Wout, bout, ws);
    globe_mfma<<<N_T, BLK, 0, stream>>>(
        pts, ctr, nrm, areas, rlen, bout, ps, pb, vs, vb, ws, (float*)d_out);
}

// Round 7
// 145.834 us; speedup vs baseline: 1.3032x; 1.3032x over previous
//
#include <hip/hip_runtime.h>
#include <hip/hip_fp16.h>

// GLOBE_61864708931733 — R23: LDS z-table replaces exp2+rcp tanh.
// R20-R22 post-mortem: attr map complete — default == waves_per_eu(4) ==
// launch_bounds(128,4) -> 64-VGPR budget -> 450MB spill. ONLY
// __launch_bounds__(BLK,2) gives the 128-VGPR budget fitting natural 116.
// Occupancy axis closed; revert to R19 config.
// R23: per-SIMD cost model (validated R16-R19): VALU busy 78k cy, ~80k-worth
// is tanh issue (3072 wave-ops x 26cy; exp2=16, rcp=8 on quarter-rate trans).
// Consumer needs only f16 z=1/(2^x+1) -> tabulate: x in [-16,16], h=1/128,
// 4096 x u16 = 8KB LDS, filled once per block (~1k cy). Per tanh:
// fma+med3+cvt+lshl = 8cy VALU + ds_read_u16 on the IDLE LDS pipe.
// Quant err <= 6.8e-4 in z (~f16 rounding scale). VALU 78k -> ~45k.
// Predicted: globe ~28-34us, LDS_Block ~16.5KB, VGPR 116-124,
// BANK_CONFLICT up 10-50x (benign), absmax ~0.25-0.30.

#define N_T 2048
#define N_S 512
#define BLK 128
#define SCALE 2.885390081777927f   // 2*log2(e)

// d_ws: 4 copies, stride 5888 floats (23552 B):
//   units 0..21: f16x4-frag pairs, unit u = [64 lanes][16 B]
//     u 0..1:  W1 (unit0: mt0 lo / mt1 hi; unit1: mt2/mt3), kt=0 only
//     u 2..9:  W2' = -2*W2*SCALE: unit 2+mt*2+kp = K=32 frag (mt, kk=kp) f16x8
//     u 10..17: W3' same
//     u 18..19: Wout' hi | u 20..21: Wout' lo   (Wout' = -2*Wout, unscaled)
//   floats 5632..5823: scaled biases [3][64]; b2',b3' include +colsum(W)
//   floats 5824..5826: bout' = bout + colsum(Wout)  (unscaled)
#define CPY_F 5888     // floats per copy
#define CPY_U 1472     // 16B units per copy

typedef _Float16 f16;
typedef _Float16 f16x4 __attribute__((ext_vector_type(4)));
typedef _Float16 f16x8 __attribute__((ext_vector_type(8)));
typedef float f32x4 __attribute__((ext_vector_type(4)));
typedef unsigned short u16;
typedef unsigned int u32;

__device__ __forceinline__ float zsig(float x) {
    // exact z = 1/(2^x+1) — used only for the one-time table fill.
    float e = __builtin_amdgcn_exp2f(x);
    return __builtin_amdgcn_rcpf(e + 1.0f);
}

__device__ __forceinline__ f32x4 mfma16(f16x4 a, f16x4 b, f32x4 c) {
    return __builtin_amdgcn_mfma_f32_16x16x16f16(a, b, c, 0, 0, 0);
}
__device__ __forceinline__ f32x4 mfma32(f16x8 a, f16x8 b, f32x4 c) {
    return __builtin_amdgcn_mfma_f32_16x16x32_f16(a, b, c, 0, 0, 0);
}

__device__ __forceinline__ u32 pkrtz(float a, float b) {
    return __builtin_bit_cast(u32, __builtin_amdgcn_cvt_pkrtz(a, b));
}

__device__ __forceinline__ f16x4 lo4(uint4 g) {
    uint2 p; p.x = g.x; p.y = g.y;
    return __builtin_bit_cast(f16x4, p);
}
__device__ __forceinline__ f16x4 hi4(uint4 g) {
    uint2 p; p.x = g.z; p.y = g.w;
    return __builtin_bit_cast(f16x4, p);
}
__device__ __forceinline__ f16x8 all8(uint4 g) {
    return __builtin_bit_cast(f16x8, g);
}

// table lookup: z(x) ~ ztab[clamp(round(x*128+2048))]  (x = SCALE*y)
__device__ __forceinline__ u32 zlut(const u16* zt, float x) {
    float v = fmaf(x, 128.0f, 2048.5f);             // +.5: trunc -> round
    v = __builtin_amdgcn_fmed3f(v, 0.5f, 4095.5f);  // clamp to table
    return (u32)zt[(u32)v];
}

// 8 z-lookups -> one K=32 B-frag (f16x8) built directly as a uint4.
__device__ __forceinline__ f16x8 ztab8(const u16* zt, f32x4 cl, f32x4 ch) {
    uint4 p;
    p.x = zlut(zt, cl[0]) | (zlut(zt, cl[1]) << 16);
    p.y = zlut(zt, cl[2]) | (zlut(zt, cl[3]) << 16);
    p.z = zlut(zt, ch[0]) | (zlut(zt, ch[1]) << 16);
    p.w = zlut(zt, ch[2]) | (zlut(zt, ch[3]) << 16);
    return __builtin_bit_cast(f16x8, p);
}

__global__ __launch_bounds__(256) void prep_kernel(
    const float* __restrict__ W1, const float* __restrict__ b1,
    const float* __restrict__ W2, const float* __restrict__ b2,
    const float* __restrict__ W3, const float* __restrict__ b3,
    const float* __restrict__ Wout, const float* __restrict__ bout,
    float* __restrict__ ws)
{
    const int tid = blockIdx.x * 256 + threadIdx.x;   // grid 26*256 = 6656
    if (tid < 5632) {                                 // 4 copies * 22 units * 64
        const int cpy = tid / 1408;
        const int r   = tid - cpy * 1408;
        const int u   = r >> 6, lane = r & 63;
        const int q = lane >> 4, l15 = lane & 15;
        float x[8];
        bool lo = false;
        #pragma unroll
        for (int e = 0; e < 8; ++e) {
            const int half = e >> 2, j = e & 3;
            float v;
            if (u < 2) {                       // W1: kt=0; frags mt = u*2+half
                const int mt = u * 2 + half;
                const int k = q * 4 + j;
                v = (k < 7) ? W1[k * 64 + mt * 16 + l15] * SCALE : 0.f;
            } else if (u < 10) {               // W2' = -2*W2*SCALE
                const int idx = u - 2, mt = idx >> 1, kp = idx & 1;
                const int k = (kp * 2 + half) * 16 + q * 4 + j;
                v = -2.0f * W2[k * 64 + mt * 16 + l15] * SCALE;
            } else if (u < 18) {               // W3' = -2*W3*SCALE
                const int idx = u - 10, mt = idx >> 1, kp = idx & 1;
                const int k = (kp * 2 + half) * 16 + q * 4 + j;
                v = -2.0f * W3[k * 64 + mt * 16 + l15] * SCALE;
            } else {                           // Wout' hi (18,19) / lo (20,21)
                const int kp = (u - 18) & 1;
                const int k = (kp * 2 + half) * 16 + q * 4 + j;
                v = (l15 < 3) ? -2.0f * Wout[k * 3 + l15] : 0.f;
                lo = (u >= 20);
            }
            x[e] = v;
        }
        u16 outw[8];
        #pragma unroll
        for (int e = 0; e < 8; ++e) {
            const f16 h = (f16)x[e];
            const f16 val = lo ? (f16)(x[e] - (float)h) : h;
            outw[e] = __builtin_bit_cast(u16, val);
        }
        uint4 g;
        g.x = outw[0] | ((u32)outw[1] << 16);
        g.y = outw[2] | ((u32)outw[3] << 16);
        g.z = outw[4] | ((u32)outw[5] << 16);
        g.w = outw[6] | ((u32)outw[7] << 16);
        *(uint4*)((char*)ws + (size_t)cpy * CPY_F * 4 + (size_t)(u * 64 + lane) * 16) = g;
    } else if (tid < 6412) {                   // biases: 4 copies * 195
        const int b = tid - 5632;
        const int cpy = b / 195, i = b - cpy * 195;
        if (i < 192) {
            const int Lb = i >> 6, j = i & 63;
            float bv;
            if (Lb == 0) {
                bv = b1[j];
            } else if (Lb == 1) {              // b2' = b2 + colsum(W2)
                bv = b2[j];
                for (int k = 0; k < 64; ++k) bv += W2[k * 64 + j];
            } else {                           // b3' = b3 + colsum(W3)
                bv = b3[j];
                for (int k = 0; k < 64; ++k) bv += W3[k * 64 + j];
            }
            ws[cpy * CPY_F + 5632 + i] = bv * SCALE;
        } else {                               // bout' = bout + colsum(Wout)
            const int c3 = i - 192;            // 0..2
            float bv = bout[c3];
            for (int k = 0; k < 64; ++k) bv += Wout[k * 3 + c3];
            ws[cpy * CPY_F + 5824 + c3] = bv;  // unscaled
        }
    }
}

__global__ __launch_bounds__(BLK, 2) void globe_mfma(
    const float* __restrict__ pts, const float* __restrict__ ctr,
    const float* __restrict__ nrm, const float* __restrict__ areas,
    const float* __restrict__ rlen, const float* __restrict__ bout,
    const float* __restrict__ p_scale, const float* __restrict__ p_bias,
    const float* __restrict__ v_scale, const float* __restrict__ v_bias,
    const float* __restrict__ ws,
    float* __restrict__ out)
{
    __shared__ __align__(16) u16 featL[2][2][64][8];   // [wave][stream]
    __shared__ __align__(16) uint4 geomL[2][2][64];
    __shared__ __align__(4) u16 ztab[4096];            // z(x), x=-16..16, h=1/128
    __shared__ float xr[4];

    const int tid  = threadIdx.x;
    const int lane = tid & 63;
    const int wv   = tid >> 6;
    const int l15  = lane & 15;
    const int q    = lane >> 4;
    const int qf   = q & 1;                          // clamped feature octet
    const int t    = blockIdx.x;                     // both waves: same target

    // ---- one-time z-table fill (both waves) ----
    #pragma unroll
    for (int i = tid; i < 4096; i += BLK) {
        const float x = fmaf((float)i, 1.0f / 128.0f, -16.0f);
        ztab[i] = __builtin_bit_cast(u16, (f16)zsig(x));
    }

    const float px = pts[3 * t + 0], py = pts[3 * t + 1], pz = pts[3 * t + 2];
    const float invL0 = __builtin_amdgcn_rcpf(rlen[0]);
    const float invL1 = __builtin_amdgcn_rcpf(rlen[1]);
    f32x4 co_init = (f32x4){0.f, 0.f, 0.f, 0.f};
    if (q == 0) { co_init[0] = ws[5824]; co_init[1] = ws[5825]; co_init[2] = ws[5826]; }

    const f16x4 bz = (f16x4){0, 0, 0, 0};
    float accp = 0.f, avx = 0.f, avy = 0.f, avz = 0.f;

    const int stag = (wv + (int)blockIdx.x) & 1;     // phase stagger

    __syncthreads();                                 // table ready

    #pragma unroll 1
    for (int cc = 0; cc < 2; ++cc) {
        const int ch = cc ^ stag;
        // chunk-dependent weight copy (copies 0,2 used): defeats LICM
        const uint4* __restrict__ wsU = (const uint4*)ws + (ch * 2) * CPY_U;
        const float* __restrict__ wsBias = ws + (ch * 2) * CPY_F + 5632;

        // ---- features + geometry for BOTH streams ----
        #pragma unroll
        for (int st = 0; st < 2; ++st) {
            const int s = (wv * 4 + ch * 2 + st) * 64 + lane;
            const float cx = ctr[3 * s + 0], cy = ctr[3 * s + 1], cz = ctr[3 * s + 2];
            const float snx = nrm[3 * s + 0], sny = nrm[3 * s + 1], snz = nrm[3 * s + 2];
            const float ar = areas[s];
            const float rvx = px - cx, rvy = py - cy, rvz = pz - cz;
            const float r2 = rvx * rvx + rvy * rvy + rvz * rvz;
            const float r2e = r2 + 1e-8f;
            const float rinv = __builtin_amdgcn_rsqf(r2e);
            const float r = r2e * rinv;
            const float rhx = rvx * rinv, rhy = rvy * rinv, rhz = rvz * rinv;
            const float cth = rhx * snx + rhy * sny + rhz * snz;
            const float c2 = cth * cth;
            const float decay = ar * __builtin_amdgcn_rcpf(r2 + 1.0f);
            uint4 fw;
            fw.x = pkrtz(__builtin_amdgcn_rcpf(fmaf(r, invL0, 1.0f)),
                         __builtin_amdgcn_rcpf(fmaf(r, invL1, 1.0f)));
            fw.y = pkrtz(1.0f, cth);
            fw.z = pkrtz(fmaf(1.5f, c2, -0.5f), cth * fmaf(2.5f, c2, -1.5f));
            fw.w = pkrtz(__logf(ar), 0.0f);
            *(uint4*)&featL[wv][st][lane][0] = fw;
            uint4 g;
            g.x = __builtin_bit_cast(u32, decay);
            g.y = pkrtz(rhx, rhy);
            g.z = pkrtz(rhz, snx);
            g.w = pkrtz(sny, snz);
            geomL[wv][st][lane] = g;
        }

        // ---- layer 1 (16x16x16, K=7 padded; shared frags, both streams) ----
        f16x8 B2[2][2][4];   // [stream][kk][n4]  (K=32 z-frags for layer 2)
        {
            const uint4 g0 = wsU[0 * 64 + lane], g1 = wsU[1 * 64 + lane];
            f16x4 a1[4];
            a1[0] = lo4(g0); a1[1] = hi4(g0); a1[2] = lo4(g1); a1[3] = hi4(g1);
            float4 bv[4];
            #pragma unroll
            for (int mt = 0; mt < 4; ++mt)
                bv[mt] = *(const float4*)(wsBias + 0 * 64 + mt * 16 + q * 4);
            #pragma unroll
            for (int n4 = 0; n4 < 4; ++n4) {
                f16x4 bf[2];
                #pragma unroll
                for (int st = 0; st < 2; ++st) {
                    const f16x4 lv = *(const f16x4*)&featL[wv][st][n4 * 16 + l15][qf * 4];
                    bf[st] = (q < 2) ? lv : bz;
                }
                f32x4 c[2][4];
                #pragma unroll
                for (int mt = 0; mt < 4; ++mt) {
                    c[0][mt] = (f32x4){bv[mt].x, bv[mt].y, bv[mt].z, bv[mt].w};
                    c[1][mt] = c[0][mt];
                    c[0][mt] = mfma16(a1[mt], bf[0], c[0][mt]);
                    c[1][mt] = mfma16(a1[mt], bf[1], c[1][mt]);
                }
                #pragma unroll
                for (int kk = 0; kk < 2; ++kk) {
                    B2[0][kk][n4] = ztab8(ztab, c[0][2 * kk], c[0][2 * kk + 1]);
                    B2[1][kk][n4] = ztab8(ztab, c[1][2 * kk], c[1][2 * kk + 1]);
                }
            }
        }

        // ---- layer 2 (16x16x32) ----
        f16x8 B3[2][2][4];
        {
            f16x8 a[4][2];
            #pragma unroll
            for (int mt = 0; mt < 4; ++mt) {
                a[mt][0] = all8(wsU[(2 + 2 * mt) * 64 + lane]);
                a[mt][1] = all8(wsU[(3 + 2 * mt) * 64 + lane]);
            }
            float4 bv[4];
            #pragma unroll
            for (int mt = 0; mt < 4; ++mt)
                bv[mt] = *(const float4*)(wsBias + 1 * 64 + mt * 16 + q * 4);
            #pragma unroll
            for (int n4 = 0; n4 < 4; ++n4) {
                f32x4 c[2][4];
                #pragma unroll
                for (int mt = 0; mt < 4; ++mt) {
                    c[0][mt] = (f32x4){bv[mt].x, bv[mt].y, bv[mt].z, bv[mt].w};
                    c[1][mt] = c[0][mt];
                }
                #pragma unroll
                for (int kk = 0; kk < 2; ++kk)
                    #pragma unroll
                    for (int mt = 0; mt < 4; ++mt) {
                        c[0][mt] = mfma32(a[mt][kk], B2[0][kk][n4], c[0][mt]);
                        c[1][mt] = mfma32(a[mt][kk], B2[1][kk][n4], c[1][mt]);
                    }
                #pragma unroll
                for (int kk = 0; kk < 2; ++kk) {
                    B3[0][kk][n4] = ztab8(ztab, c[0][2 * kk], c[0][2 * kk + 1]);
                    B3[1][kk][n4] = ztab8(ztab, c[1][2 * kk], c[1][2 * kk + 1]);
                }
            }
        }

        // ---- layer 3 (16x16x32) ----
        f16x8 BO[2][2][4];
        {
            f16x8 a[4][2];
            #pragma unroll
            for (int mt = 0; mt < 4; ++mt) {
                a[mt][0] = all8(wsU[(10 + 2 * mt) * 64 + lane]);
                a[mt][1] = all8(wsU[(11 + 2 * mt) * 64 + lane]);
            }
            float4 bv[4];
            #pragma unroll
            for (int mt = 0; mt < 4; ++mt)
                bv[mt] = *(const float4*)(wsBias + 2 * 64 + mt * 16 + q * 4);
            #pragma unroll
            for (int n4 = 0; n4 < 4; ++n4) {
                f32x4 c[2][4];
                #pragma unroll
                for (int mt = 0; mt < 4; ++mt) {
                    c[0][mt] = (f32x4){bv[mt].x, bv[mt].y, bv[mt].z, bv[mt].w};
                    c[1][mt] = c[0][mt];
                }
                #pragma unroll
                for (int kk = 0; kk < 2; ++kk)
                    #pragma unroll
                    for (int mt = 0; mt < 4; ++mt) {
                        c[0][mt] = mfma32(a[mt][kk], B3[0][kk][n4], c[0][mt]);
                        c[1][mt] = mfma32(a[mt][kk], B3[1][kk][n4], c[1][mt]);
                    }
                #pragma unroll
                for (int kk = 0; kk < 2; ++kk) {
                    BO[0][kk][n4] = ztab8(ztab, c[0][2 * kk], c[0][2 * kk + 1]);
                    BO[1][kk][n4] = ztab8(ztab, c[1][2 * kk], c[1][2 * kk + 1]);
                }
            }
        }

        // ---- output layer (16x16x32, hi+lo) + decay-weighted accumulation ----
        {
            const f16x8 aoh0 = all8(wsU[18 * 64 + lane]);
            const f16x8 aoh1 = all8(wsU[19 * 64 + lane]);
            const f16x8 aol0 = all8(wsU[20 * 64 + lane]);
            const f16x8 aol1 = all8(wsU[21 * 64 + lane]);
            #pragma unroll
            for (int n4 = 0; n4 < 4; ++n4) {
                f32x4 co[2];
                co[0] = co_init; co[1] = co_init;
                co[0] = mfma32(aoh0, BO[0][0][n4], co[0]);
                co[1] = mfma32(aoh0, BO[1][0][n4], co[1]);
                co[0] = mfma32(aol0, BO[0][0][n4], co[0]);
                co[1] = mfma32(aol0, BO[1][0][n4], co[1]);
                co[0] = mfma32(aoh1, BO[0][1][n4], co[0]);
                co[1] = mfma32(aoh1, BO[1][1][n4], co[1]);
                co[0] = mfma32(aol1, BO[0][1][n4], co[0]);
                co[1] = mfma32(aol1, BO[1][1][n4], co[1]);
                if (q == 0) {
                    #pragma unroll
                    for (int st = 0; st < 2; ++st) {
                        const uint4 g = geomL[wv][st][n4 * 16 + l15];
                        const float d = __builtin_bit_cast(float, g.x);
                        const float2 rxy = __half22float2(__builtin_bit_cast(__half2, g.y));
                        const float2 rzx = __half22float2(__builtin_bit_cast(__half2, g.z));
                        const float2 nyz = __half22float2(__builtin_bit_cast(__half2, g.w));
                        const float o0 = co[st][0], o1 = co[st][1], o2 = co[st][2];
                        accp = fmaf(o0, d, accp);
                        avx  = fmaf(fmaf(o1, rxy.x, o2 * rzx.y), d, avx);
                        avy  = fmaf(fmaf(o1, rxy.y, o2 * nyz.x), d, avy);
                        avz  = fmaf(fmaf(o1, rzx.x, o2 * nyz.y), d, avz);
                    }
                }
            }
        }
    }

    // ---- reduce across the 16 accumulating lanes ----
    #pragma unroll
    for (int off = 8; off > 0; off >>= 1) {
        accp += __shfl_down(accp, off);
        avx  += __shfl_down(avx,  off);
        avy  += __shfl_down(avy,  off);
        avz  += __shfl_down(avz,  off);
    }

    // ---- cross-wave combine ----
    if (wv == 1 && lane == 0) {
        xr[0] = accp; xr[1] = avx; xr[2] = avy; xr[3] = avz;
    }
    __syncthreads();
    if (wv == 0 && lane == 0) {
        accp += xr[0]; avx += xr[1]; avy += xr[2]; avz += xr[3];
        const float ps = p_scale[0], pb = p_bias[0];
        const float vs = v_scale[0], vb = v_bias[0];
        out[4 * t + 0] = fmaf(accp, ps, pb);
        out[4 * t + 1] = fmaf(avx, vs, vb);
        out[4 * t + 2] = fmaf(avy, vs, vb);
        out[4 * t + 3] = fmaf(avz, vs, vb);
    }
}

extern "C" void kernel_launch(void* const* d_in, const int* in_sizes, int n_in,
                              void* d_out, int out_size, void* d_ws, size_t ws_size,
                              hipStream_t stream) {
    (void)in_sizes; (void)n_in; (void)ws_size; (void)out_size;
    const float* pts   = (const float*)d_in[0];
    const float* ctr   = (const float*)d_in[1];
    const float* nrm   = (const float*)d_in[2];
    const float* areas = (const float*)d_in[3];
    const float* rlen  = (const float*)d_in[4];
    const float* W1    = (const float*)d_in[5];
    const float* b1    = (const float*)d_in[6];
    const float* W2    = (const float*)d_in[7];
    const float* b2    = (const float*)d_in[8];
    const float* W3    = (const float*)d_in[9];
    const float* b3    = (const float*)d_in[10];
    const float* Wout  = (const float*)d_in[11];
    const float* bout  = (const float*)d_in[12];
    const float* ps    = (const float*)d_in[13];
    const float* pb    = (const float*)d_in[14];
    const float* vs    = (const float*)d_in[15];
    const float* vb    = (const float*)d_in[16];
    float* ws = (float*)d_ws;

    prep_kernel<<<26, 256, 0, stream>>>(W1, b1, W2, b2, W3, b3, Wout, bout, ws);
    globe_mfma<<<N_T, BLK, 0, stream>>>(
        pts, ctr, nrm, areas, rlen, bout, ps, pb, vs, vb, ws, (float*)d_out);
}

// Round 8
// 139.339 us; speedup vs baseline: 1.3640x; 1.0466x over previous
//
#include <hip/hip_runtime.h>
#include <hip/hip_fp16.h>

// GLOBE_61864708931733 — R24: revert LUT (R23 failed), R19 + s_setprio.
// R23 post-mortem (65.5us): VALU busy IDENTICAL to R19 (78.4k vs 79.5k
// cy/SIMD) despite removing all trans ops -> gfx950 trans issue at ~normal
// VALU rate; the exp2=16cy model was WRONG. LUT only added scalar ds_read
// gathers (bank conflict 655k -> 13.6M) + serial read->pack chain = +8us.
// zsig (exp2+add+rcp) is already near-minimal op count. Wins R16-R19 were
// op-count/chain cuts, not trans-specific.
// R24 = R19 exactly + s_setprio(1) around MFMA-phase regions (T5): stagger
// makes co-resident waves phase-diverse; prioritizing the MFMA-phase wave
// lets its mfma chain issue ahead, the other wave's tanh fills VALU idle
// (37k cy/SIMD).
// Predicted: globe 53-57us (neutral 57-59 => declare R19 converged),
// VGPR ~116, LDS 8704, conflicts ~655k, absmax 0.25.

#define N_T 2048
#define N_S 512
#define BLK 128
#define SCALE 2.885390081777927f   // 2*log2(e)

// d_ws: 4 copies, stride 5888 floats (23552 B):
//   units 0..21: f16x4-frag pairs, unit u = [64 lanes][16 B]
//     u 0..1:  W1 (unit0: mt0 lo / mt1 hi; unit1: mt2/mt3), kt=0 only
//     u 2..9:  W2' = -2*W2*SCALE: unit 2+mt*2+kp = K=32 frag (mt, kk=kp) f16x8
//     u 10..17: W3' same
//     u 18..19: Wout' hi | u 20..21: Wout' lo   (Wout' = -2*Wout, unscaled)
//   floats 5632..5823: scaled biases [3][64]; b2',b3' include +colsum(W)
//   floats 5824..5826: bout' = bout + colsum(Wout)  (unscaled)
#define CPY_F 5888     // floats per copy
#define CPY_U 1472     // 16B units per copy

typedef _Float16 f16;
typedef _Float16 f16x4 __attribute__((ext_vector_type(4)));
typedef _Float16 f16x8 __attribute__((ext_vector_type(8)));
typedef float f32x4 __attribute__((ext_vector_type(4)));
typedef unsigned short u16;
typedef unsigned int u32;

__device__ __forceinline__ float zsig(float x) {
    // x is SCALE*y; z = 1/(2^x+1); consumer weights are folded so t = 1-2z.
    float e = __builtin_amdgcn_exp2f(x);
    return __builtin_amdgcn_rcpf(e + 1.0f);
}

__device__ __forceinline__ f32x4 mfma16(f16x4 a, f16x4 b, f32x4 c) {
    return __builtin_amdgcn_mfma_f32_16x16x16f16(a, b, c, 0, 0, 0);
}
__device__ __forceinline__ f32x4 mfma32(f16x8 a, f16x8 b, f32x4 c) {
    return __builtin_amdgcn_mfma_f32_16x16x32_f16(a, b, c, 0, 0, 0);
}

__device__ __forceinline__ u32 pkrtz(float a, float b) {
    return __builtin_bit_cast(u32, __builtin_amdgcn_cvt_pkrtz(a, b));
}

__device__ __forceinline__ f16x4 lo4(uint4 g) {
    uint2 p; p.x = g.x; p.y = g.y;
    return __builtin_bit_cast(f16x4, p);
}
__device__ __forceinline__ f16x4 hi4(uint4 g) {
    uint2 p; p.x = g.z; p.y = g.w;
    return __builtin_bit_cast(f16x4, p);
}
__device__ __forceinline__ f16x8 all8(uint4 g) {
    return __builtin_bit_cast(f16x8, g);
}

// 8 z-sigmoids -> one K=32 B-frag (f16x8) built directly as a uint4.
__device__ __forceinline__ f16x8 tpack8(f32x4 cl, f32x4 ch) {
    uint4 p;
    p.x = pkrtz(zsig(cl[0]), zsig(cl[1]));
    p.y = pkrtz(zsig(cl[2]), zsig(cl[3]));
    p.z = pkrtz(zsig(ch[0]), zsig(ch[1]));
    p.w = pkrtz(zsig(ch[2]), zsig(ch[3]));
    return __builtin_bit_cast(f16x8, p);
}

__global__ __launch_bounds__(256) void prep_kernel(
    const float* __restrict__ W1, const float* __restrict__ b1,
    const float* __restrict__ W2, const float* __restrict__ b2,
    const float* __restrict__ W3, const float* __restrict__ b3,
    const float* __restrict__ Wout, const float* __restrict__ bout,
    float* __restrict__ ws)
{
    const int tid = blockIdx.x * 256 + threadIdx.x;   // grid 26*256 = 6656
    if (tid < 5632) {                                 // 4 copies * 22 units * 64
        const int cpy = tid / 1408;
        const int r   = tid - cpy * 1408;
        const int u   = r >> 6, lane = r & 63;
        const int q = lane >> 4, l15 = lane & 15;
        float x[8];
        bool lo = false;
        #pragma unroll
        for (int e = 0; e < 8; ++e) {
            const int half = e >> 2, j = e & 3;
            float v;
            if (u < 2) {                       // W1: kt=0; frags mt = u*2+half
                const int mt = u * 2 + half;
                const int k = q * 4 + j;
                v = (k < 7) ? W1[k * 64 + mt * 16 + l15] * SCALE : 0.f;
            } else if (u < 10) {               // W2' = -2*W2*SCALE
                const int idx = u - 2, mt = idx >> 1, kp = idx & 1;
                const int k = (kp * 2 + half) * 16 + q * 4 + j;
                v = -2.0f * W2[k * 64 + mt * 16 + l15] * SCALE;
            } else if (u < 18) {               // W3' = -2*W3*SCALE
                const int idx = u - 10, mt = idx >> 1, kp = idx & 1;
                const int k = (kp * 2 + half) * 16 + q * 4 + j;
                v = -2.0f * W3[k * 64 + mt * 16 + l15] * SCALE;
            } else {                           // Wout' hi (18,19) / lo (20,21)
                const int kp = (u - 18) & 1;
                const int k = (kp * 2 + half) * 16 + q * 4 + j;
                v = (l15 < 3) ? -2.0f * Wout[k * 3 + l15] : 0.f;
                lo = (u >= 20);
            }
            x[e] = v;
        }
        u16 outw[8];
        #pragma unroll
        for (int e = 0; e < 8; ++e) {
            const f16 h = (f16)x[e];
            const f16 val = lo ? (f16)(x[e] - (float)h) : h;
            outw[e] = __builtin_bit_cast(u16, val);
        }
        uint4 g;
        g.x = outw[0] | ((u32)outw[1] << 16);
        g.y = outw[2] | ((u32)outw[3] << 16);
        g.z = outw[4] | ((u32)outw[5] << 16);
        g.w = outw[6] | ((u32)outw[7] << 16);
        *(uint4*)((char*)ws + (size_t)cpy * CPY_F * 4 + (size_t)(u * 64 + lane) * 16) = g;
    } else if (tid < 6412) {                   // biases: 4 copies * 195
        const int b = tid - 5632;
        const int cpy = b / 195, i = b - cpy * 195;
        if (i < 192) {
            const int Lb = i >> 6, j = i & 63;
            float bv;
            if (Lb == 0) {
                bv = b1[j];
            } else if (Lb == 1) {              // b2' = b2 + colsum(W2)
                bv = b2[j];
                for (int k = 0; k < 64; ++k) bv += W2[k * 64 + j];
            } else {                           // b3' = b3 + colsum(W3)
                bv = b3[j];
                for (int k = 0; k < 64; ++k) bv += W3[k * 64 + j];
            }
            ws[cpy * CPY_F + 5632 + i] = bv * SCALE;
        } else {                               // bout' = bout + colsum(Wout)
            const int c3 = i - 192;            // 0..2
            float bv = bout[c3];
            for (int k = 0; k < 64; ++k) bv += Wout[k * 3 + c3];
            ws[cpy * CPY_F + 5824 + c3] = bv;  // unscaled
        }
    }
}

__global__ __launch_bounds__(BLK, 2) void globe_mfma(
    const float* __restrict__ pts, const float* __restrict__ ctr,
    const float* __restrict__ nrm, const float* __restrict__ areas,
    const float* __restrict__ rlen, const float* __restrict__ bout,
    const float* __restrict__ p_scale, const float* __restrict__ p_bias,
    const float* __restrict__ v_scale, const float* __restrict__ v_bias,
    const float* __restrict__ ws,
    float* __restrict__ out)
{
    __shared__ __align__(16) u16 featL[2][2][64][8];   // [wave][stream]
    __shared__ __align__(16) uint4 geomL[2][2][64];
    __shared__ float xr[4];

    const int tid  = threadIdx.x;
    const int lane = tid & 63;
    const int wv   = tid >> 6;
    const int l15  = lane & 15;
    const int q    = lane >> 4;
    const int qf   = q & 1;                          // clamped feature octet
    const int t    = blockIdx.x;                     // both waves: same target

    const float px = pts[3 * t + 0], py = pts[3 * t + 1], pz = pts[3 * t + 2];
    const float invL0 = __builtin_amdgcn_rcpf(rlen[0]);
    const float invL1 = __builtin_amdgcn_rcpf(rlen[1]);
    f32x4 co_init = (f32x4){0.f, 0.f, 0.f, 0.f};
    if (q == 0) { co_init[0] = ws[5824]; co_init[1] = ws[5825]; co_init[2] = ws[5826]; }

    const f16x4 bz = (f16x4){0, 0, 0, 0};
    float accp = 0.f, avx = 0.f, avy = 0.f, avz = 0.f;

    const int stag = (wv + (int)blockIdx.x) & 1;     // phase stagger

    #pragma unroll 1
    for (int cc = 0; cc < 2; ++cc) {
        const int ch = cc ^ stag;
        // chunk-dependent weight copy (copies 0,2 used): defeats LICM
        const uint4* __restrict__ wsU = (const uint4*)ws + (ch * 2) * CPY_U;
        const float* __restrict__ wsBias = ws + (ch * 2) * CPY_F + 5632;

        // ---- features + geometry for BOTH streams ----
        #pragma unroll
        for (int st = 0; st < 2; ++st) {
            const int s = (wv * 4 + ch * 2 + st) * 64 + lane;
            const float cx = ctr[3 * s + 0], cy = ctr[3 * s + 1], cz = ctr[3 * s + 2];
            const float snx = nrm[3 * s + 0], sny = nrm[3 * s + 1], snz = nrm[3 * s + 2];
            const float ar = areas[s];
            const float rvx = px - cx, rvy = py - cy, rvz = pz - cz;
            const float r2 = rvx * rvx + rvy * rvy + rvz * rvz;
            const float r2e = r2 + 1e-8f;
            const float rinv = __builtin_amdgcn_rsqf(r2e);
            const float r = r2e * rinv;
            const float rhx = rvx * rinv, rhy = rvy * rinv, rhz = rvz * rinv;
            const float cth = rhx * snx + rhy * sny + rhz * snz;
            const float c2 = cth * cth;
            const float decay = ar * __builtin_amdgcn_rcpf(r2 + 1.0f);
            uint4 fw;
            fw.x = pkrtz(__builtin_amdgcn_rcpf(fmaf(r, invL0, 1.0f)),
                         __builtin_amdgcn_rcpf(fmaf(r, invL1, 1.0f)));
            fw.y = pkrtz(1.0f, cth);
            fw.z = pkrtz(fmaf(1.5f, c2, -0.5f), cth * fmaf(2.5f, c2, -1.5f));
            fw.w = pkrtz(__logf(ar), 0.0f);
            *(uint4*)&featL[wv][st][lane][0] = fw;
            uint4 g;
            g.x = __builtin_bit_cast(u32, decay);
            g.y = pkrtz(rhx, rhy);
            g.z = pkrtz(rhz, snx);
            g.w = pkrtz(sny, snz);
            geomL[wv][st][lane] = g;
        }

        // ---- layer 1 (16x16x16, K=7 padded; shared frags, both streams) ----
        f16x8 B2[2][2][4];   // [stream][kk][n4]  (K=32 z-frags for layer 2)
        {
            const uint4 g0 = wsU[0 * 64 + lane], g1 = wsU[1 * 64 + lane];
            f16x4 a1[4];
            a1[0] = lo4(g0); a1[1] = hi4(g0); a1[2] = lo4(g1); a1[3] = hi4(g1);
            float4 bv[4];
            #pragma unroll
            for (int mt = 0; mt < 4; ++mt)
                bv[mt] = *(const float4*)(wsBias + 0 * 64 + mt * 16 + q * 4);
            #pragma unroll
            for (int n4 = 0; n4 < 4; ++n4) {
                f16x4 bf[2];
                #pragma unroll
                for (int st = 0; st < 2; ++st) {
                    const f16x4 lv = *(const f16x4*)&featL[wv][st][n4 * 16 + l15][qf * 4];
                    bf[st] = (q < 2) ? lv : bz;
                }
                f32x4 c[2][4];
                __builtin_amdgcn_s_setprio(1);
                #pragma unroll
                for (int mt = 0; mt < 4; ++mt) {
                    c[0][mt] = (f32x4){bv[mt].x, bv[mt].y, bv[mt].z, bv[mt].w};
                    c[1][mt] = c[0][mt];
                    c[0][mt] = mfma16(a1[mt], bf[0], c[0][mt]);
                    c[1][mt] = mfma16(a1[mt], bf[1], c[1][mt]);
                }
                __builtin_amdgcn_s_setprio(0);
                #pragma unroll
                for (int kk = 0; kk < 2; ++kk) {
                    B2[0][kk][n4] = tpack8(c[0][2 * kk], c[0][2 * kk + 1]);
                    B2[1][kk][n4] = tpack8(c[1][2 * kk], c[1][2 * kk + 1]);
                }
            }
        }

        // ---- layer 2 (16x16x32) ----
        f16x8 B3[2][2][4];
        {
            f16x8 a[4][2];
            #pragma unroll
            for (int mt = 0; mt < 4; ++mt) {
                a[mt][0] = all8(wsU[(2 + 2 * mt) * 64 + lane]);
                a[mt][1] = all8(wsU[(3 + 2 * mt) * 64 + lane]);
            }
            float4 bv[4];
            #pragma unroll
            for (int mt = 0; mt < 4; ++mt)
                bv[mt] = *(const float4*)(wsBias + 1 * 64 + mt * 16 + q * 4);
            #pragma unroll
            for (int n4 = 0; n4 < 4; ++n4) {
                f32x4 c[2][4];
                #pragma unroll
                for (int mt = 0; mt < 4; ++mt) {
                    c[0][mt] = (f32x4){bv[mt].x, bv[mt].y, bv[mt].z, bv[mt].w};
                    c[1][mt] = c[0][mt];
                }
                __builtin_amdgcn_s_setprio(1);
                #pragma unroll
                for (int kk = 0; kk < 2; ++kk)
                    #pragma unroll
                    for (int mt = 0; mt < 4; ++mt) {
                        c[0][mt] = mfma32(a[mt][kk], B2[0][kk][n4], c[0][mt]);
                        c[1][mt] = mfma32(a[mt][kk], B2[1][kk][n4], c[1][mt]);
                    }
                __builtin_amdgcn_s_setprio(0);
                #pragma unroll
                for (int kk = 0; kk < 2; ++kk) {
                    B3[0][kk][n4] = tpack8(c[0][2 * kk], c[0][2 * kk + 1]);
                    B3[1][kk][n4] = tpack8(c[1][2 * kk], c[1][2 * kk + 1]);
                }
            }
        }

        // ---- layer 3 (16x16x32) ----
        f16x8 BO[2][2][4];
        {
            f16x8 a[4][2];
            #pragma unroll
            for (int mt = 0; mt < 4; ++mt) {
                a[mt][0] = all8(wsU[(10 + 2 * mt) * 64 + lane]);
                a[mt][1] = all8(wsU[(11 + 2 * mt) * 64 + lane]);
            }
            float4 bv[4];
            #pragma unroll
            for (int mt = 0; mt < 4; ++mt)
                bv[mt] = *(const float4*)(wsBias + 2 * 64 + mt * 16 + q * 4);
            #pragma unroll
            for (int n4 = 0; n4 < 4; ++n4) {
                f32x4 c[2][4];
                #pragma unroll
                for (int mt = 0; mt < 4; ++mt) {
                    c[0][mt] = (f32x4){bv[mt].x, bv[mt].y, bv[mt].z, bv[mt].w};
                    c[1][mt] = c[0][mt];
                }
                __builtin_amdgcn_s_setprio(1);
                #pragma unroll
                for (int kk = 0; kk < 2; ++kk)
                    #pragma unroll
                    for (int mt = 0; mt < 4; ++mt) {
                        c[0][mt] = mfma32(a[mt][kk], B3[0][kk][n4], c[0][mt]);
                        c[1][mt] = mfma32(a[mt][kk], B3[1][kk][n4], c[1][mt]);
                    }
                __builtin_amdgcn_s_setprio(0);
                #pragma unroll
                for (int kk = 0; kk < 2; ++kk) {
                    BO[0][kk][n4] = tpack8(c[0][2 * kk], c[0][2 * kk + 1]);
                    BO[1][kk][n4] = tpack8(c[1][2 * kk], c[1][2 * kk + 1]);
                }
            }
        }

        // ---- output layer (16x16x32, hi+lo) + decay-weighted accumulation ----
        {
            const f16x8 aoh0 = all8(wsU[18 * 64 + lane]);
            const f16x8 aoh1 = all8(wsU[19 * 64 + lane]);
            const f16x8 aol0 = all8(wsU[20 * 64 + lane]);
            const f16x8 aol1 = all8(wsU[21 * 64 + lane]);
            #pragma unroll
            for (int n4 = 0; n4 < 4; ++n4) {
                f32x4 co[2];
                co[0] = co_init; co[1] = co_init;
                __builtin_amdgcn_s_setprio(1);
                co[0] = mfma32(aoh0, BO[0][0][n4], co[0]);
                co[1] = mfma32(aoh0, BO[1][0][n4], co[1]);
                co[0] = mfma32(aol0, BO[0][0][n4], co[0]);
                co[1] = mfma32(aol0, BO[1][0][n4], co[1]);
                co[0] = mfma32(aoh1, BO[0][1][n4], co[0]);
                co[1] = mfma32(aoh1, BO[1][1][n4], co[1]);
                co[0] = mfma32(aol1, BO[0][1][n4], co[0]);
                co[1] = mfma32(aol1, BO[1][1][n4], co[1]);
                __builtin_amdgcn_s_setprio(0);
                if (q == 0) {
                    #pragma unroll
                    for (int st = 0; st < 2; ++st) {
                        const uint4 g = geomL[wv][st][n4 * 16 + l15];
                        const float d = __builtin_bit_cast(float, g.x);
                        const float2 rxy = __half22float2(__builtin_bit_cast(__half2, g.y));
                        const float2 rzx = __half22float2(__builtin_bit_cast(__half2, g.z));
                        const float2 nyz = __half22float2(__builtin_bit_cast(__half2, g.w));
                        const float o0 = co[st][0], o1 = co[st][1], o2 = co[st][2];
                        accp = fmaf(o0, d, accp);
                        avx  = fmaf(fmaf(o1, rxy.x, o2 * rzx.y), d, avx);
                        avy  = fmaf(fmaf(o1, rxy.y, o2 * nyz.x), d, avy);
                        avz  = fmaf(fmaf(o1, rzx.x, o2 * nyz.y), d, avz);
                    }
                }
            }
        }
    }

    // ---- reduce across the 16 accumulating lanes ----
    #pragma unroll
    for (int off = 8; off > 0; off >>= 1) {
        accp += __shfl_down(accp, off);
        avx  += __shfl_down(avx,  off);
        avy  += __shfl_down(avy,  off);
        avz  += __shfl_down(avz,  off);
    }

    // ---- cross-wave combine ----
    if (wv == 1 && lane == 0) {
        xr[0] = accp; xr[1] = avx; xr[2] = avy; xr[3] = avz;
    }
    __syncthreads();
    if (wv == 0 && lane == 0) {
        accp += xr[0]; avx += xr[1]; avy += xr[2]; avz += xr[3];
        const float ps = p_scale[0], pb = p_bias[0];
        const float vs = v_scale[0], vb = v_bias[0];
        out[4 * t + 0] = fmaf(accp, ps, pb);
        out[4 * t + 1] = fmaf(avx, vs, vb);
        out[4 * t + 2] = fmaf(avy, vs, vb);
        out[4 * t + 3] = fmaf(avz, vs, vb);
    }
}

extern "C" void kernel_launch(void* const* d_in, const int* in_sizes, int n_in,
                              void* d_out, int out_size, void* d_ws, size_t ws_size,
                              hipStream_t stream) {
    (void)in_sizes; (void)n_in; (void)ws_size; (void)out_size;
    const float* pts   = (const float*)d_in[0];
    const float* ctr   = (const float*)d_in[1];
    const float* nrm   = (const float*)d_in[2];
    const float* areas = (const float*)d_in[3];
    const float* rlen  = (const float*)d_in[4];
    const float* W1    = (const float*)d_in[5];
    const float* b1    = (const float*)d_in[6];
    const float* W2    = (const float*)d_in[7];
    const float* b2    = (const float*)d_in[8];
    const float* W3    = (const float*)d_in[9];
    const float* b3    = (const float*)d_in[10];
    const float* Wout  = (const float*)d_in[11];
    const float* bout  = (const float*)d_in[12];
    const float* ps    = (const float*)d_in[13];
    const float* pb    = (const float*)d_in[14];
    const float* vs    = (const float*)d_in[15];
    const float* vb    = (const float*)d_in[16];
    float* ws = (float*)d_ws;

    prep_kernel<<<26, 256, 0, stream>>>(W1, b1, W2, b2, W3, b3, Wout, bout, ws);
    globe_mfma<<<N_T, BLK, 0, stream>>>(
        pts, ctr, nrm, areas, rlen, bout, ps, pb, vs, vb, ws, (float*)d_out);
}

// Round 9
// 133.572 us; speedup vs baseline: 1.4229x; 1.0432x over previous
//
#include <hip/hip_runtime.h>
#include <hip/hip_fp16.h>

// GLOBE_61864708931733 — R25: waves_per_eu(2,8) — min for regalloc, max for
// residency. R24 post-mortem (59.8us): setprio NEGATIVE (+2.1us vs R19) —
// at ~1.3 resident waves/SIMD there's no second wave to arbitrate; pure
// overhead. Removed.
// Attr map (4 data points): hipcc translates __launch_bounds__(B,w) to
// amdgpu-waves-per-eu=w,w — min AND max. (128,2): VGPR 116 but residency
// HARD-CAPPED at 2/EU (occ 15.5%). min>=4 or unset: budget 64 -> spill
// (occ 37-42% proves cap is metadata-driven). Never tested: min=2,max=8 —
// regalloc budgets for min (>=128 VGPR -> natural 116, codegen==R19),
// max lifts the clamp (HW allows 4/SIMD at 116 VGPR; grid = 16 waves/CU).
// R25 = R19 + amdgpu_waves_per_eu(2,8). No setprio.
// Predicted: VGPR ~116, FETCH ~475KB, Occ 30-45%, globe 44-50us.
// If VGPR 64/spill: compiler used max for budget -> revert, declare R19.
// If occ/dur unchanged: residency not attr-capped -> R19 converged.

#define N_T 2048
#define N_S 512
#define BLK 128
#define SCALE 2.885390081777927f   // 2*log2(e)

// d_ws: 4 copies, stride 5888 floats (23552 B):
//   units 0..21: f16x4-frag pairs, unit u = [64 lanes][16 B]
//     u 0..1:  W1 (unit0: mt0 lo / mt1 hi; unit1: mt2/mt3), kt=0 only
//     u 2..9:  W2' = -2*W2*SCALE: unit 2+mt*2+kp = K=32 frag (mt, kk=kp) f16x8
//     u 10..17: W3' same
//     u 18..19: Wout' hi | u 20..21: Wout' lo   (Wout' = -2*Wout, unscaled)
//   floats 5632..5823: scaled biases [3][64]; b2',b3' include +colsum(W)
//   floats 5824..5826: bout' = bout + colsum(Wout)  (unscaled)
#define CPY_F 5888     // floats per copy
#define CPY_U 1472     // 16B units per copy

typedef _Float16 f16;
typedef _Float16 f16x4 __attribute__((ext_vector_type(4)));
typedef _Float16 f16x8 __attribute__((ext_vector_type(8)));
typedef float f32x4 __attribute__((ext_vector_type(4)));
typedef unsigned short u16;
typedef unsigned int u32;

__device__ __forceinline__ float zsig(float x) {
    // x is SCALE*y; z = 1/(2^x+1); consumer weights are folded so t = 1-2z.
    float e = __builtin_amdgcn_exp2f(x);
    return __builtin_amdgcn_rcpf(e + 1.0f);
}

__device__ __forceinline__ f32x4 mfma16(f16x4 a, f16x4 b, f32x4 c) {
    return __builtin_amdgcn_mfma_f32_16x16x16f16(a, b, c, 0, 0, 0);
}
__device__ __forceinline__ f32x4 mfma32(f16x8 a, f16x8 b, f32x4 c) {
    return __builtin_amdgcn_mfma_f32_16x16x32_f16(a, b, c, 0, 0, 0);
}

__device__ __forceinline__ u32 pkrtz(float a, float b) {
    return __builtin_bit_cast(u32, __builtin_amdgcn_cvt_pkrtz(a, b));
}

__device__ __forceinline__ f16x4 lo4(uint4 g) {
    uint2 p; p.x = g.x; p.y = g.y;
    return __builtin_bit_cast(f16x4, p);
}
__device__ __forceinline__ f16x4 hi4(uint4 g) {
    uint2 p; p.x = g.z; p.y = g.w;
    return __builtin_bit_cast(f16x4, p);
}
__device__ __forceinline__ f16x8 all8(uint4 g) {
    return __builtin_bit_cast(f16x8, g);
}

// 8 z-sigmoids -> one K=32 B-frag (f16x8) built directly as a uint4.
__device__ __forceinline__ f16x8 tpack8(f32x4 cl, f32x4 ch) {
    uint4 p;
    p.x = pkrtz(zsig(cl[0]), zsig(cl[1]));
    p.y = pkrtz(zsig(cl[2]), zsig(cl[3]));
    p.z = pkrtz(zsig(ch[0]), zsig(ch[1]));
    p.w = pkrtz(zsig(ch[2]), zsig(ch[3]));
    return __builtin_bit_cast(f16x8, p);
}

__global__ __launch_bounds__(256) void prep_kernel(
    const float* __restrict__ W1, const float* __restrict__ b1,
    const float* __restrict__ W2, const float* __restrict__ b2,
    const float* __restrict__ W3, const float* __restrict__ b3,
    const float* __restrict__ Wout, const float* __restrict__ bout,
    float* __restrict__ ws)
{
    const int tid = blockIdx.x * 256 + threadIdx.x;   // grid 26*256 = 6656
    if (tid < 5632) {                                 // 4 copies * 22 units * 64
        const int cpy = tid / 1408;
        const int r   = tid - cpy * 1408;
        const int u   = r >> 6, lane = r & 63;
        const int q = lane >> 4, l15 = lane & 15;
        float x[8];
        bool lo = false;
        #pragma unroll
        for (int e = 0; e < 8; ++e) {
            const int half = e >> 2, j = e & 3;
            float v;
            if (u < 2) {                       // W1: kt=0; frags mt = u*2+half
                const int mt = u * 2 + half;
                const int k = q * 4 + j;
                v = (k < 7) ? W1[k * 64 + mt * 16 + l15] * SCALE : 0.f;
            } else if (u < 10) {               // W2' = -2*W2*SCALE
                const int idx = u - 2, mt = idx >> 1, kp = idx & 1;
                const int k = (kp * 2 + half) * 16 + q * 4 + j;
                v = -2.0f * W2[k * 64 + mt * 16 + l15] * SCALE;
            } else if (u < 18) {               // W3' = -2*W3*SCALE
                const int idx = u - 10, mt = idx >> 1, kp = idx & 1;
                const int k = (kp * 2 + half) * 16 + q * 4 + j;
                v = -2.0f * W3[k * 64 + mt * 16 + l15] * SCALE;
            } else {                           // Wout' hi (18,19) / lo (20,21)
                const int kp = (u - 18) & 1;
                const int k = (kp * 2 + half) * 16 + q * 4 + j;
                v = (l15 < 3) ? -2.0f * Wout[k * 3 + l15] : 0.f;
                lo = (u >= 20);
            }
            x[e] = v;
        }
        u16 outw[8];
        #pragma unroll
        for (int e = 0; e < 8; ++e) {
            const f16 h = (f16)x[e];
            const f16 val = lo ? (f16)(x[e] - (float)h) : h;
            outw[e] = __builtin_bit_cast(u16, val);
        }
        uint4 g;
        g.x = outw[0] | ((u32)outw[1] << 16);
        g.y = outw[2] | ((u32)outw[3] << 16);
        g.z = outw[4] | ((u32)outw[5] << 16);
        g.w = outw[6] | ((u32)outw[7] << 16);
        *(uint4*)((char*)ws + (size_t)cpy * CPY_F * 4 + (size_t)(u * 64 + lane) * 16) = g;
    } else if (tid < 6412) {                   // biases: 4 copies * 195
        const int b = tid - 5632;
        const int cpy = b / 195, i = b - cpy * 195;
        if (i < 192) {
            const int Lb = i >> 6, j = i & 63;
            float bv;
            if (Lb == 0) {
                bv = b1[j];
            } else if (Lb == 1) {              // b2' = b2 + colsum(W2)
                bv = b2[j];
                for (int k = 0; k < 64; ++k) bv += W2[k * 64 + j];
            } else {                           // b3' = b3 + colsum(W3)
                bv = b3[j];
                for (int k = 0; k < 64; ++k) bv += W3[k * 64 + j];
            }
            ws[cpy * CPY_F + 5632 + i] = bv * SCALE;
        } else {                               // bout' = bout + colsum(Wout)
            const int c3 = i - 192;            // 0..2
            float bv = bout[c3];
            for (int k = 0; k < 64; ++k) bv += Wout[k * 3 + c3];
            ws[cpy * CPY_F + 5824 + c3] = bv;  // unscaled
        }
    }
}

__global__
__attribute__((amdgpu_flat_work_group_size(BLK, BLK)))
__attribute__((amdgpu_waves_per_eu(2, 8)))   // min 2 (regalloc: 116 fits), max 8 (no clamp)
void globe_mfma(
    const float* __restrict__ pts, const float* __restrict__ ctr,
    const float* __restrict__ nrm, const float* __restrict__ areas,
    const float* __restrict__ rlen, const float* __restrict__ bout,
    const float* __restrict__ p_scale, const float* __restrict__ p_bias,
    const float* __restrict__ v_scale, const float* __restrict__ v_bias,
    const float* __restrict__ ws,
    float* __restrict__ out)
{
    __shared__ __align__(16) u16 featL[2][2][64][8];   // [wave][stream]
    __shared__ __align__(16) uint4 geomL[2][2][64];
    __shared__ float xr[4];

    const int tid  = threadIdx.x;
    const int lane = tid & 63;
    const int wv   = tid >> 6;
    const int l15  = lane & 15;
    const int q    = lane >> 4;
    const int qf   = q & 1;                          // clamped feature octet
    const int t    = blockIdx.x;                     // both waves: same target

    const float px = pts[3 * t + 0], py = pts[3 * t + 1], pz = pts[3 * t + 2];
    const float invL0 = __builtin_amdgcn_rcpf(rlen[0]);
    const float invL1 = __builtin_amdgcn_rcpf(rlen[1]);
    f32x4 co_init = (f32x4){0.f, 0.f, 0.f, 0.f};
    if (q == 0) { co_init[0] = ws[5824]; co_init[1] = ws[5825]; co_init[2] = ws[5826]; }

    const f16x4 bz = (f16x4){0, 0, 0, 0};
    float accp = 0.f, avx = 0.f, avy = 0.f, avz = 0.f;

    const int stag = (wv + (int)blockIdx.x) & 1;     // phase stagger

    #pragma unroll 1
    for (int cc = 0; cc < 2; ++cc) {
        const int ch = cc ^ stag;
        // chunk-dependent weight copy (copies 0,2 used): defeats LICM
        const uint4* __restrict__ wsU = (const uint4*)ws + (ch * 2) * CPY_U;
        const float* __restrict__ wsBias = ws + (ch * 2) * CPY_F + 5632;

        // ---- features + geometry for BOTH streams ----
        #pragma unroll
        for (int st = 0; st < 2; ++st) {
            const int s = (wv * 4 + ch * 2 + st) * 64 + lane;
            const float cx = ctr[3 * s + 0], cy = ctr[3 * s + 1], cz = ctr[3 * s + 2];
            const float snx = nrm[3 * s + 0], sny = nrm[3 * s + 1], snz = nrm[3 * s + 2];
            const float ar = areas[s];
            const float rvx = px - cx, rvy = py - cy, rvz = pz - cz;
            const float r2 = rvx * rvx + rvy * rvy + rvz * rvz;
            const float r2e = r2 + 1e-8f;
            const float rinv = __builtin_amdgcn_rsqf(r2e);
            const float r = r2e * rinv;
            const float rhx = rvx * rinv, rhy = rvy * rinv, rhz = rvz * rinv;
            const float cth = rhx * snx + rhy * sny + rhz * snz;
            const float c2 = cth * cth;
            const float decay = ar * __builtin_amdgcn_rcpf(r2 + 1.0f);
            uint4 fw;
            fw.x = pkrtz(__builtin_amdgcn_rcpf(fmaf(r, invL0, 1.0f)),
                         __builtin_amdgcn_rcpf(fmaf(r, invL1, 1.0f)));
            fw.y = pkrtz(1.0f, cth);
            fw.z = pkrtz(fmaf(1.5f, c2, -0.5f), cth * fmaf(2.5f, c2, -1.5f));
            fw.w = pkrtz(__logf(ar), 0.0f);
            *(uint4*)&featL[wv][st][lane][0] = fw;
            uint4 g;
            g.x = __builtin_bit_cast(u32, decay);
            g.y = pkrtz(rhx, rhy);
            g.z = pkrtz(rhz, snx);
            g.w = pkrtz(sny, snz);
            geomL[wv][st][lane] = g;
        }

        // ---- layer 1 (16x16x16, K=7 padded; shared frags, both streams) ----
        f16x8 B2[2][2][4];   // [stream][kk][n4]  (K=32 z-frags for layer 2)
        {
            const uint4 g0 = wsU[0 * 64 + lane], g1 = wsU[1 * 64 + lane];
            f16x4 a1[4];
            a1[0] = lo4(g0); a1[1] = hi4(g0); a1[2] = lo4(g1); a1[3] = hi4(g1);
            float4 bv[4];
            #pragma unroll
            for (int mt = 0; mt < 4; ++mt)
                bv[mt] = *(const float4*)(wsBias + 0 * 64 + mt * 16 + q * 4);
            #pragma unroll
            for (int n4 = 0; n4 < 4; ++n4) {
                f16x4 bf[2];
                #pragma unroll
                for (int st = 0; st < 2; ++st) {
                    const f16x4 lv = *(const f16x4*)&featL[wv][st][n4 * 16 + l15][qf * 4];
                    bf[st] = (q < 2) ? lv : bz;
                }
                f32x4 c[2][4];
                #pragma unroll
                for (int mt = 0; mt < 4; ++mt) {
                    c[0][mt] = (f32x4){bv[mt].x, bv[mt].y, bv[mt].z, bv[mt].w};
                    c[1][mt] = c[0][mt];
                    c[0][mt] = mfma16(a1[mt], bf[0], c[0][mt]);
                    c[1][mt] = mfma16(a1[mt], bf[1], c[1][mt]);
                }
                #pragma unroll
                for (int kk = 0; kk < 2; ++kk) {
                    B2[0][kk][n4] = tpack8(c[0][2 * kk], c[0][2 * kk + 1]);
                    B2[1][kk][n4] = tpack8(c[1][2 * kk], c[1][2 * kk + 1]);
                }
            }
        }

        // ---- layer 2 (16x16x32) ----
        f16x8 B3[2][2][4];
        {
            f16x8 a[4][2];
            #pragma unroll
            for (int mt = 0; mt < 4; ++mt) {
                a[mt][0] = all8(wsU[(2 + 2 * mt) * 64 + lane]);
                a[mt][1] = all8(wsU[(3 + 2 * mt) * 64 + lane]);
            }
            float4 bv[4];
            #pragma unroll
            for (int mt = 0; mt < 4; ++mt)
                bv[mt] = *(const float4*)(wsBias + 1 * 64 + mt * 16 + q * 4);
            #pragma unroll
            for (int n4 = 0; n4 < 4; ++n4) {
                f32x4 c[2][4];
                #pragma unroll
                for (int mt = 0; mt < 4; ++mt) {
                    c[0][mt] = (f32x4){bv[mt].x, bv[mt].y, bv[mt].z, bv[mt].w};
                    c[1][mt] = c[0][mt];
                }
                #pragma unroll
                for (int kk = 0; kk < 2; ++kk)
                    #pragma unroll
                    for (int mt = 0; mt < 4; ++mt) {
                        c[0][mt] = mfma32(a[mt][kk], B2[0][kk][n4], c[0][mt]);
                        c[1][mt] = mfma32(a[mt][kk], B2[1][kk][n4], c[1][mt]);
                    }
                #pragma unroll
                for (int kk = 0; kk < 2; ++kk) {
                    B3[0][kk][n4] = tpack8(c[0][2 * kk], c[0][2 * kk + 1]);
                    B3[1][kk][n4] = tpack8(c[1][2 * kk], c[1][2 * kk + 1]);
                }
            }
        }

        // ---- layer 3 (16x16x32) ----
        f16x8 BO[2][2][4];
        {
            f16x8 a[4][2];
            #pragma unroll
            for (int mt = 0; mt < 4; ++mt) {
                a[mt][0] = all8(wsU[(10 + 2 * mt) * 64 + lane]);
                a[mt][1] = all8(wsU[(11 + 2 * mt) * 64 + lane]);
            }
            float4 bv[4];
            #pragma unroll
            for (int mt = 0; mt < 4; ++mt)
                bv[mt] = *(const float4*)(wsBias + 2 * 64 + mt * 16 + q * 4);
            #pragma unroll
            for (int n4 = 0; n4 < 4; ++n4) {
                f32x4 c[2][4];
                #pragma unroll
                for (int mt = 0; mt < 4; ++mt) {
                    c[0][mt] = (f32x4){bv[mt].x, bv[mt].y, bv[mt].z, bv[mt].w};
                    c[1][mt] = c[0][mt];
                }
                #pragma unroll
                for (int kk = 0; kk < 2; ++kk)
                    #pragma unroll
                    for (int mt = 0; mt < 4; ++mt) {
                        c[0][mt] = mfma32(a[mt][kk], B3[0][kk][n4], c[0][mt]);
                        c[1][mt] = mfma32(a[mt][kk], B3[1][kk][n4], c[1][mt]);
                    }
                #pragma unroll
                for (int kk = 0; kk < 2; ++kk) {
                    BO[0][kk][n4] = tpack8(c[0][2 * kk], c[0][2 * kk + 1]);
                    BO[1][kk][n4] = tpack8(c[1][2 * kk], c[1][2 * kk + 1]);
                }
            }
        }

        // ---- output layer (16x16x32, hi+lo) + decay-weighted accumulation ----
        {
            const f16x8 aoh0 = all8(wsU[18 * 64 + lane]);
            const f16x8 aoh1 = all8(wsU[19 * 64 + lane]);
            const f16x8 aol0 = all8(wsU[20 * 64 + lane]);
            const f16x8 aol1 = all8(wsU[21 * 64 + lane]);
            #pragma unroll
            for (int n4 = 0; n4 < 4; ++n4) {
                f32x4 co[2];
                co[0] = co_init; co[1] = co_init;
                co[0] = mfma32(aoh0, BO[0][0][n4], co[0]);
                co[1] = mfma32(aoh0, BO[1][0][n4], co[1]);
                co[0] = mfma32(aol0, BO[0][0][n4], co[0]);
                co[1] = mfma32(aol0, BO[1][0][n4], co[1]);
                co[0] = mfma32(aoh1, BO[0][1][n4], co[0]);
                co[1] = mfma32(aoh1, BO[1][1][n4], co[1]);
                co[0] = mfma32(aol1, BO[0][1][n4], co[0]);
                co[1] = mfma32(aol1, BO[1][1][n4], co[1]);
                if (q == 0) {
                    #pragma unroll
                    for (int st = 0; st < 2; ++st) {
                        const uint4 g = geomL[wv][st][n4 * 16 + l15];
                        const float d = __builtin_bit_cast(float, g.x);
                        const float2 rxy = __half22float2(__builtin_bit_cast(__half2, g.y));
                        const float2 rzx = __half22float2(__builtin_bit_cast(__half2, g.z));
                        const float2 nyz = __half22float2(__builtin_bit_cast(__half2, g.w));
                        const float o0 = co[st][0], o1 = co[st][1], o2 = co[st][2];
                        accp = fmaf(o0, d, accp);
                        avx  = fmaf(fmaf(o1, rxy.x, o2 * rzx.y), d, avx);
                        avy  = fmaf(fmaf(o1, rxy.y, o2 * nyz.x), d, avy);
                        avz  = fmaf(fmaf(o1, rzx.x, o2 * nyz.y), d, avz);
                    }
                }
            }
        }
    }

    // ---- reduce across the 16 accumulating lanes ----
    #pragma unroll
    for (int off = 8; off > 0; off >>= 1) {
        accp += __shfl_down(accp, off);
        avx  += __shfl_down(avx,  off);
        avy  += __shfl_down(avy,  off);
        avz  += __shfl_down(avz,  off);
    }

    // ---- cross-wave combine ----
    if (wv == 1 && lane == 0) {
        xr[0] = accp; xr[1] = avx; xr[2] = avy; xr[3] = avz;
    }
    __syncthreads();
    if (wv == 0 && lane == 0) {
        accp += xr[0]; avx += xr[1]; avy += xr[2]; avz += xr[3];
        const float ps = p_scale[0], pb = p_bias[0];
        const float vs = v_scale[0], vb = v_bias[0];
        out[4 * t + 0] = fmaf(accp, ps, pb);
        out[4 * t + 1] = fmaf(avx, vs, vb);
        out[4 * t + 2] = fmaf(avy, vs, vb);
        out[4 * t + 3] = fmaf(avz, vs, vb);
    }
}

extern "C" void kernel_launch(void* const* d_in, const int* in_sizes, int n_in,
                              void* d_out, int out_size, void* d_ws, size_t ws_size,
                              hipStream_t stream) {
    (void)in_sizes; (void)n_in; (void)ws_size; (void)out_size;
    const float* pts   = (const float*)d_in[0];
    const float* ctr   = (const float*)d_in[1];
    const float* nrm   = (const float*)d_in[2];
    const float* areas = (const float*)d_in[3];
    const float* rlen  = (const float*)d_in[4];
    const float* W1    = (const float*)d_in[5];
    const float* b1    = (const float*)d_in[6];
    const float* W2    = (const float*)d_in[7];
    const float* b2    = (const float*)d_in[8];
    const float* W3    = (const float*)d_in[9];
    const float* b3    = (const float*)d_in[10];
    const float* Wout  = (const float*)d_in[11];
    const float* bout  = (const float*)d_in[12];
    const float* ps    = (const float*)d_in[13];
    const float* pb    = (const float*)d_in[14];
    const float* vs    = (const float*)d_in[15];
    const float* vb    = (const float*)d_in[16];
    float* ws = (float*)d_ws;

    prep_kernel<<<26, 256, 0, stream>>>(W1, b1, W2, b2, W3, b3, Wout, bout, ws);
    globe_mfma<<<N_T, BLK, 0, stream>>>(
        pts, ctr, nrm, areas, rlen, bout, ps, pb, vs, vb, ws, (float*)d_out);
}

// Round 10
// 130.610 us; speedup vs baseline: 1.4551x; 1.0227x over previous
//
#include <hip/hip_runtime.h>
#include <hip/hip_fp16.h>

// GLOBE_61864708931733 — R26: 1-wave workgroups (4096 blocks) + atomic combine.
// R25 post-mortem (58.2us): waves_per_eu(2,8) gave intended codegen (VGPR 116,
// no spill) and max=8 allowed — occupancy STILL 15%, dur == R19. Residency is
// NOT attr-capped; HW holds ~2.4 blocks/CU regardless. VALU 79k + MFMA 23k =
// 102k vs wall 139k cy/SIMD -> doubling residency would give ~43us. Last
// untested residency lever: workgroup granularity. Every round used 2-wave
// blocks; the ~2.4/CU plateau may be per-WG scheduler behavior.
// R26: block b -> target t=b>>1, half h=b&1 (replaces wv). Same per-wave work
// and codegen; no __syncthreads; LDS 4.3KB; combine via 4 atomicAdd into out
// (zeroed by prep; h==0 adds p_bias/v_bias). Stagger = (h+t)&1.
// Predicted if granularity was the limiter: Occ 25-40%, globe 45-52us.
// If neutral (~56-60, occ ~15%): cap is uncontrollable -> declare converged.

#define N_T 2048
#define N_S 512
#define BLK 64
#define SCALE 2.885390081777927f   // 2*log2(e)

// d_ws: 4 copies, stride 5888 floats (23552 B):
//   units 0..21: f16x4-frag pairs, unit u = [64 lanes][16 B]
//     u 0..1:  W1 (unit0: mt0 lo / mt1 hi; unit1: mt2/mt3), kt=0 only
//     u 2..9:  W2' = -2*W2*SCALE: unit 2+mt*2+kp = K=32 frag (mt, kk=kp) f16x8
//     u 10..17: W3' same
//     u 18..19: Wout' hi | u 20..21: Wout' lo   (Wout' = -2*Wout, unscaled)
//   floats 5632..5823: scaled biases [3][64]; b2',b3' include +colsum(W)
//   floats 5824..5826: bout' = bout + colsum(Wout)  (unscaled)
#define CPY_F 5888     // floats per copy
#define CPY_U 1472     // 16B units per copy

typedef _Float16 f16;
typedef _Float16 f16x4 __attribute__((ext_vector_type(4)));
typedef _Float16 f16x8 __attribute__((ext_vector_type(8)));
typedef float f32x4 __attribute__((ext_vector_type(4)));
typedef unsigned short u16;
typedef unsigned int u32;

__device__ __forceinline__ float zsig(float x) {
    // x is SCALE*y; z = 1/(2^x+1); consumer weights are folded so t = 1-2z.
    float e = __builtin_amdgcn_exp2f(x);
    return __builtin_amdgcn_rcpf(e + 1.0f);
}

__device__ __forceinline__ f32x4 mfma16(f16x4 a, f16x4 b, f32x4 c) {
    return __builtin_amdgcn_mfma_f32_16x16x16f16(a, b, c, 0, 0, 0);
}
__device__ __forceinline__ f32x4 mfma32(f16x8 a, f16x8 b, f32x4 c) {
    return __builtin_amdgcn_mfma_f32_16x16x32_f16(a, b, c, 0, 0, 0);
}

__device__ __forceinline__ u32 pkrtz(float a, float b) {
    return __builtin_bit_cast(u32, __builtin_amdgcn_cvt_pkrtz(a, b));
}

__device__ __forceinline__ f16x4 lo4(uint4 g) {
    uint2 p; p.x = g.x; p.y = g.y;
    return __builtin_bit_cast(f16x4, p);
}
__device__ __forceinline__ f16x4 hi4(uint4 g) {
    uint2 p; p.x = g.z; p.y = g.w;
    return __builtin_bit_cast(f16x4, p);
}
__device__ __forceinline__ f16x8 all8(uint4 g) {
    return __builtin_bit_cast(f16x8, g);
}

// 8 z-sigmoids -> one K=32 B-frag (f16x8) built directly as a uint4.
__device__ __forceinline__ f16x8 tpack8(f32x4 cl, f32x4 ch) {
    uint4 p;
    p.x = pkrtz(zsig(cl[0]), zsig(cl[1]));
    p.y = pkrtz(zsig(cl[2]), zsig(cl[3]));
    p.z = pkrtz(zsig(ch[0]), zsig(ch[1]));
    p.w = pkrtz(zsig(ch[2]), zsig(ch[3]));
    return __builtin_bit_cast(f16x8, p);
}

__global__ __launch_bounds__(256) void prep_kernel(
    const float* __restrict__ W1, const float* __restrict__ b1,
    const float* __restrict__ W2, const float* __restrict__ b2,
    const float* __restrict__ W3, const float* __restrict__ b3,
    const float* __restrict__ Wout, const float* __restrict__ bout,
    float* __restrict__ ws, float* __restrict__ outp)
{
    const int tid = blockIdx.x * 256 + threadIdx.x;   // grid 33*256 = 8448
    if (tid < 8192) outp[tid] = 0.f;                  // zero out for atomics
    if (tid < 5632) {                                 // 4 copies * 22 units * 64
        const int cpy = tid / 1408;
        const int r   = tid - cpy * 1408;
        const int u   = r >> 6, lane = r & 63;
        const int q = lane >> 4, l15 = lane & 15;
        float x[8];
        bool lo = false;
        #pragma unroll
        for (int e = 0; e < 8; ++e) {
            const int half = e >> 2, j = e & 3;
            float v;
            if (u < 2) {                       // W1: kt=0; frags mt = u*2+half
                const int mt = u * 2 + half;
                const int k = q * 4 + j;
                v = (k < 7) ? W1[k * 64 + mt * 16 + l15] * SCALE : 0.f;
            } else if (u < 10) {               // W2' = -2*W2*SCALE
                const int idx = u - 2, mt = idx >> 1, kp = idx & 1;
                const int k = (kp * 2 + half) * 16 + q * 4 + j;
                v = -2.0f * W2[k * 64 + mt * 16 + l15] * SCALE;
            } else if (u < 18) {               // W3' = -2*W3*SCALE
                const int idx = u - 10, mt = idx >> 1, kp = idx & 1;
                const int k = (kp * 2 + half) * 16 + q * 4 + j;
                v = -2.0f * W3[k * 64 + mt * 16 + l15] * SCALE;
            } else {                           // Wout' hi (18,19) / lo (20,21)
                const int kp = (u - 18) & 1;
                const int k = (kp * 2 + half) * 16 + q * 4 + j;
                v = (l15 < 3) ? -2.0f * Wout[k * 3 + l15] : 0.f;
                lo = (u >= 20);
            }
            x[e] = v;
        }
        u16 outw[8];
        #pragma unroll
        for (int e = 0; e < 8; ++e) {
            const f16 h = (f16)x[e];
            const f16 val = lo ? (f16)(x[e] - (float)h) : h;
            outw[e] = __builtin_bit_cast(u16, val);
        }
        uint4 g;
        g.x = outw[0] | ((u32)outw[1] << 16);
        g.y = outw[2] | ((u32)outw[3] << 16);
        g.z = outw[4] | ((u32)outw[5] << 16);
        g.w = outw[6] | ((u32)outw[7] << 16);
        *(uint4*)((char*)ws + (size_t)cpy * CPY_F * 4 + (size_t)(u * 64 + lane) * 16) = g;
    } else if (tid < 6412) {                   // biases: 4 copies * 195
        const int b = tid - 5632;
        const int cpy = b / 195, i = b - cpy * 195;
        if (i < 192) {
            const int Lb = i >> 6, j = i & 63;
            float bv;
            if (Lb == 0) {
                bv = b1[j];
            } else if (Lb == 1) {              // b2' = b2 + colsum(W2)
                bv = b2[j];
                for (int k = 0; k < 64; ++k) bv += W2[k * 64 + j];
            } else {                           // b3' = b3 + colsum(W3)
                bv = b3[j];
                for (int k = 0; k < 64; ++k) bv += W3[k * 64 + j];
            }
            ws[cpy * CPY_F + 5632 + i] = bv * SCALE;
        } else {                               // bout' = bout + colsum(Wout)
            const int c3 = i - 192;            // 0..2
            float bv = bout[c3];
            for (int k = 0; k < 64; ++k) bv += Wout[k * 3 + c3];
            ws[cpy * CPY_F + 5824 + c3] = bv;  // unscaled
        }
    }
}

__global__ __launch_bounds__(BLK, 2) void globe_mfma(
    const float* __restrict__ pts, const float* __restrict__ ctr,
    const float* __restrict__ nrm, const float* __restrict__ areas,
    const float* __restrict__ rlen, const float* __restrict__ bout,
    const float* __restrict__ p_scale, const float* __restrict__ p_bias,
    const float* __restrict__ v_scale, const float* __restrict__ v_bias,
    const float* __restrict__ ws,
    float* __restrict__ out)
{
    __shared__ __align__(16) u16 featL[2][64][8];      // [stream]
    __shared__ __align__(16) uint4 geomL[2][64];

    const int lane = threadIdx.x & 63;
    const int l15  = lane & 15;
    const int q    = lane >> 4;
    const int qf   = q & 1;                          // clamped feature octet
    const int b    = blockIdx.x;                     // 4096 blocks
    const int t    = b >> 1;                         // target
    const int h    = b & 1;                          // source half (was wv)

    const float px = pts[3 * t + 0], py = pts[3 * t + 1], pz = pts[3 * t + 2];
    const float invL0 = __builtin_amdgcn_rcpf(rlen[0]);
    const float invL1 = __builtin_amdgcn_rcpf(rlen[1]);
    f32x4 co_init = (f32x4){0.f, 0.f, 0.f, 0.f};
    if (q == 0) { co_init[0] = ws[5824]; co_init[1] = ws[5825]; co_init[2] = ws[5826]; }

    const f16x4 bz = (f16x4){0, 0, 0, 0};
    float accp = 0.f, avx = 0.f, avy = 0.f, avz = 0.f;

    const int stag = (h + t) & 1;                    // phase stagger

    #pragma unroll 1
    for (int cc = 0; cc < 2; ++cc) {
        const int ch = cc ^ stag;
        // chunk-dependent weight copy (copies 0,2 used): defeats LICM
        const uint4* __restrict__ wsU = (const uint4*)ws + (ch * 2) * CPY_U;
        const float* __restrict__ wsBias = ws + (ch * 2) * CPY_F + 5632;

        // ---- features + geometry for BOTH streams ----
        #pragma unroll
        for (int st = 0; st < 2; ++st) {
            const int s = (h * 4 + ch * 2 + st) * 64 + lane;
            const float cx = ctr[3 * s + 0], cy = ctr[3 * s + 1], cz = ctr[3 * s + 2];
            const float snx = nrm[3 * s + 0], sny = nrm[3 * s + 1], snz = nrm[3 * s + 2];
            const float ar = areas[s];
            const float rvx = px - cx, rvy = py - cy, rvz = pz - cz;
            const float r2 = rvx * rvx + rvy * rvy + rvz * rvz;
            const float r2e = r2 + 1e-8f;
            const float rinv = __builtin_amdgcn_rsqf(r2e);
            const float r = r2e * rinv;
            const float rhx = rvx * rinv, rhy = rvy * rinv, rhz = rvz * rinv;
            const float cth = rhx * snx + rhy * sny + rhz * snz;
            const float c2 = cth * cth;
            const float decay = ar * __builtin_amdgcn_rcpf(r2 + 1.0f);
            uint4 fw;
            fw.x = pkrtz(__builtin_amdgcn_rcpf(fmaf(r, invL0, 1.0f)),
                         __builtin_amdgcn_rcpf(fmaf(r, invL1, 1.0f)));
            fw.y = pkrtz(1.0f, cth);
            fw.z = pkrtz(fmaf(1.5f, c2, -0.5f), cth * fmaf(2.5f, c2, -1.5f));
            fw.w = pkrtz(__logf(ar), 0.0f);
            *(uint4*)&featL[st][lane][0] = fw;
            uint4 g;
            g.x = __builtin_bit_cast(u32, decay);
            g.y = pkrtz(rhx, rhy);
            g.z = pkrtz(rhz, snx);
            g.w = pkrtz(sny, snz);
            geomL[st][lane] = g;
        }

        // ---- layer 1 (16x16x16, K=7 padded; shared frags, both streams) ----
        f16x8 B2[2][2][4];   // [stream][kk][n4]  (K=32 z-frags for layer 2)
        {
            const uint4 g0 = wsU[0 * 64 + lane], g1 = wsU[1 * 64 + lane];
            f16x4 a1[4];
            a1[0] = lo4(g0); a1[1] = hi4(g0); a1[2] = lo4(g1); a1[3] = hi4(g1);
            float4 bv[4];
            #pragma unroll
            for (int mt = 0; mt < 4; ++mt)
                bv[mt] = *(const float4*)(wsBias + 0 * 64 + mt * 16 + q * 4);
            #pragma unroll
            for (int n4 = 0; n4 < 4; ++n4) {
                f16x4 bf[2];
                #pragma unroll
                for (int st = 0; st < 2; ++st) {
                    const f16x4 lv = *(const f16x4*)&featL[st][n4 * 16 + l15][qf * 4];
                    bf[st] = (q < 2) ? lv : bz;
                }
                f32x4 c[2][4];
                #pragma unroll
                for (int mt = 0; mt < 4; ++mt) {
                    c[0][mt] = (f32x4){bv[mt].x, bv[mt].y, bv[mt].z, bv[mt].w};
                    c[1][mt] = c[0][mt];
                    c[0][mt] = mfma16(a1[mt], bf[0], c[0][mt]);
                    c[1][mt] = mfma16(a1[mt], bf[1], c[1][mt]);
                }
                #pragma unroll
                for (int kk = 0; kk < 2; ++kk) {
                    B2[0][kk][n4] = tpack8(c[0][2 * kk], c[0][2 * kk + 1]);
                    B2[1][kk][n4] = tpack8(c[1][2 * kk], c[1][2 * kk + 1]);
                }
            }
        }

        // ---- layer 2 (16x16x32) ----
        f16x8 B3[2][2][4];
        {
            f16x8 a[4][2];
            #pragma unroll
            for (int mt = 0; mt < 4; ++mt) {
                a[mt][0] = all8(wsU[(2 + 2 * mt) * 64 + lane]);
                a[mt][1] = all8(wsU[(3 + 2 * mt) * 64 + lane]);
            }
            float4 bv[4];
            #pragma unroll
            for (int mt = 0; mt < 4; ++mt)
                bv[mt] = *(const float4*)(wsBias + 1 * 64 + mt * 16 + q * 4);
            #pragma unroll
            for (int n4 = 0; n4 < 4; ++n4) {
                f32x4 c[2][4];
                #pragma unroll
                for (int mt = 0; mt < 4; ++mt) {
                    c[0][mt] = (f32x4){bv[mt].x, bv[mt].y, bv[mt].z, bv[mt].w};
                    c[1][mt] = c[0][mt];
                }
                #pragma unroll
                for (int kk = 0; kk < 2; ++kk)
                    #pragma unroll
                    for (int mt = 0; mt < 4; ++mt) {
                        c[0][mt] = mfma32(a[mt][kk], B2[0][kk][n4], c[0][mt]);
                        c[1][mt] = mfma32(a[mt][kk], B2[1][kk][n4], c[1][mt]);
                    }
                #pragma unroll
                for (int kk = 0; kk < 2; ++kk) {
                    B3[0][kk][n4] = tpack8(c[0][2 * kk], c[0][2 * kk + 1]);
                    B3[1][kk][n4] = tpack8(c[1][2 * kk], c[1][2 * kk + 1]);
                }
            }
        }

        // ---- layer 3 (16x16x32) ----
        f16x8 BO[2][2][4];
        {
            f16x8 a[4][2];
            #pragma unroll
            for (int mt = 0; mt < 4; ++mt) {
                a[mt][0] = all8(wsU[(10 + 2 * mt) * 64 + lane]);
                a[mt][1] = all8(wsU[(11 + 2 * mt) * 64 + lane]);
            }
            float4 bv[4];
            #pragma unroll
            for (int mt = 0; mt < 4; ++mt)
                bv[mt] = *(const float4*)(wsBias + 2 * 64 + mt * 16 + q * 4);
            #pragma unroll
            for (int n4 = 0; n4 < 4; ++n4) {
                f32x4 c[2][4];
                #pragma unroll
                for (int mt = 0; mt < 4; ++mt) {
                    c[0][mt] = (f32x4){bv[mt].x, bv[mt].y, bv[mt].z, bv[mt].w};
                    c[1][mt] = c[0][mt];
                }
                #pragma unroll
                for (int kk = 0; kk < 2; ++kk)
                    #pragma unroll
                    for (int mt = 0; mt < 4; ++mt) {
                        c[0][mt] = mfma32(a[mt][kk], B3[0][kk][n4], c[0][mt]);
                        c[1][mt] = mfma32(a[mt][kk], B3[1][kk][n4], c[1][mt]);
                    }
                #pragma unroll
                for (int kk = 0; kk < 2; ++kk) {
                    BO[0][kk][n4] = tpack8(c[0][2 * kk], c[0][2 * kk + 1]);
                    BO[1][kk][n4] = tpack8(c[1][2 * kk], c[1][2 * kk + 1]);
                }
            }
        }

        // ---- output layer (16x16x32, hi+lo) + decay-weighted accumulation ----
        {
            const f16x8 aoh0 = all8(wsU[18 * 64 + lane]);
            const f16x8 aoh1 = all8(wsU[19 * 64 + lane]);
            const f16x8 aol0 = all8(wsU[20 * 64 + lane]);
            const f16x8 aol1 = all8(wsU[21 * 64 + lane]);
            #pragma unroll
            for (int n4 = 0; n4 < 4; ++n4) {
                f32x4 co[2];
                co[0] = co_init; co[1] = co_init;
                co[0] = mfma32(aoh0, BO[0][0][n4], co[0]);
                co[1] = mfma32(aoh0, BO[1][0][n4], co[1]);
                co[0] = mfma32(aol0, BO[0][0][n4], co[0]);
                co[1] = mfma32(aol0, BO[1][0][n4], co[1]);
                co[0] = mfma32(aoh1, BO[0][1][n4], co[0]);
                co[1] = mfma32(aoh1, BO[1][1][n4], co[1]);
                co[0] = mfma32(aol1, BO[0][1][n4], co[0]);
                co[1] = mfma32(aol1, BO[1][1][n4], co[1]);
                if (q == 0) {
                    #pragma unroll
                    for (int st = 0; st < 2; ++st) {
                        const uint4 g = geomL[st][n4 * 16 + l15];
                        const float d = __builtin_bit_cast(float, g.x);
                        const float2 rxy = __half22float2(__builtin_bit_cast(__half2, g.y));
                        const float2 rzx = __half22float2(__builtin_bit_cast(__half2, g.z));
                        const float2 nyz = __half22float2(__builtin_bit_cast(__half2, g.w));
                        const float o0 = co[st][0], o1 = co[st][1], o2 = co[st][2];
                        accp = fmaf(o0, d, accp);
                        avx  = fmaf(fmaf(o1, rxy.x, o2 * rzx.y), d, avx);
                        avy  = fmaf(fmaf(o1, rxy.y, o2 * nyz.x), d, avy);
                        avz  = fmaf(fmaf(o1, rzx.x, o2 * nyz.y), d, avz);
                    }
                }
            }
        }
    }

    // ---- reduce across the 16 accumulating lanes ----
    #pragma unroll
    for (int off = 8; off > 0; off >>= 1) {
        accp += __shfl_down(accp, off);
        avx  += __shfl_down(avx,  off);
        avy  += __shfl_down(avy,  off);
        avz  += __shfl_down(avz,  off);
    }

    // ---- combine across the two half-blocks via atomics (out pre-zeroed) ----
    if (lane == 0) {
        const float ps = p_scale[0], vs = v_scale[0];
        const float bp = h ? 0.f : p_bias[0];
        const float bv = h ? 0.f : v_bias[0];
        atomicAdd(&out[4 * t + 0], fmaf(accp, ps, bp));
        atomicAdd(&out[4 * t + 1], fmaf(avx, vs, bv));
        atomicAdd(&out[4 * t + 2], fmaf(avy, vs, bv));
        atomicAdd(&out[4 * t + 3], fmaf(avz, vs, bv));
    }
}

extern "C" void kernel_launch(void* const* d_in, const int* in_sizes, int n_in,
                              void* d_out, int out_size, void* d_ws, size_t ws_size,
                              hipStream_t stream) {
    (void)in_sizes; (void)n_in; (void)ws_size; (void)out_size;
    const float* pts   = (const float*)d_in[0];
    const float* ctr   = (const float*)d_in[1];
    const float* nrm   = (const float*)d_in[2];
    const float* areas = (const float*)d_in[3];
    const float* rlen  = (const float*)d_in[4];
    const float* W1    = (const float*)d_in[5];
    const float* b1    = (const float*)d_in[6];
    const float* W2    = (const float*)d_in[7];
    const float* b2    = (const float*)d_in[8];
    const float* W3    = (const float*)d_in[9];
    const float* b3    = (const float*)d_in[10];
    const float* Wout  = (const float*)d_in[11];
    const float* bout  = (const float*)d_in[12];
    const float* ps    = (const float*)d_in[13];
    const float* pb    = (const float*)d_in[14];
    const float* vs    = (const float*)d_in[15];
    const float* vb    = (const float*)d_in[16];
    float* ws = (float*)d_ws;

    prep_kernel<<<33, 256, 0, stream>>>(W1, b1, W2, b2, W3, b3, Wout, bout, ws,
                                        (float*)d_out);
    globe_mfma<<<N_T * 2, BLK, 0, stream>>>(
        pts, ctr, nrm, areas, rlen, bout, ps, pb, vs, vb, ws, (float*)d_out);
}